// Round 7
// baseline (43.830 us; speedup 1.0000x reference)
//
#include <hip/hip_runtime.h>
#include <hip/hip_bf16.h>

// Problem constants (fixed by reference): B=8, T=2048, C=64
#define B_ 8
#define T_ 2048
#define LOG2E 1.4426950408889634f

typedef _Float16 half8 __attribute__((ext_vector_type(8)));
typedef float f32x4 __attribute__((ext_vector_type(4)));

#define MFMA16(A, Bv, Cv) __builtin_amdgcn_mfma_f32_16x16x32_f16((A), (Bv), (Cv), 0, 0, 0)

// ---------------------------------------------------------------------------
// Kernel 0: pre-pack weights. W [k][d] fp32 -> Wp [mat][d][k] f16.
// ---------------------------------------------------------------------------
__global__ __launch_bounds__(256) void prepack_kernel(
    const float* __restrict__ WM, const float* __restrict__ WN,
    const float* __restrict__ WV, _Float16* __restrict__ Wp)
{
    const int idx = blockIdx.x * 256 + threadIdx.x;   // [0, 12288)
    const int m = idx >> 12;
    const int r = idx & 4095;
    const int d = r >> 6;
    const int k = r & 63;
    const float* W = (m == 0) ? WM : (m == 1) ? WN : WV;
    Wp[m * 4096 + d * 64 + k] = (_Float16)W[k * 64 + d];
}

// ---------------------------------------------------------------------------
// Kernel 1: MFMA projections -> fragment-major K/V layouts (R6-verified).
// ---------------------------------------------------------------------------
__global__ __launch_bounds__(256) void proj_kernel(
    const float* __restrict__ F, const _Float16* __restrict__ Wp,
    _Float16* __restrict__ Qh, _Float16* __restrict__ Kf,
    _Float16* __restrict__ Vf)
{
    const int lane = threadIdx.x & 63;
    const int wid  = threadIdx.x >> 6;
    const int ql = lane & 15;
    const int g  = lane >> 4;
    const int rowbase = blockIdx.x * 64 + wid * 16;
    const int b = rowbase >> 11;

    const float* fr = F + (size_t)(rowbase + ql) * 64;
    union { f32x4 v[2]; float s[8]; } fa0, fa1;
    fa0.v[0] = *(const f32x4*)(fr + 8 * g);
    fa0.v[1] = *(const f32x4*)(fr + 8 * g + 4);
    fa1.v[0] = *(const f32x4*)(fr + 32 + 8 * g);
    fa1.v[1] = *(const f32x4*)(fr + 32 + 8 * g + 4);
    half8 af0, af1;
#pragma unroll
    for (int j = 0; j < 8; ++j) {
        af0[j] = (_Float16)fa0.s[j];
        af1[j] = (_Float16)fa1.s[j];
    }

    const half8* wq = (const half8*)(Wp);
    const half8* wk = (const half8*)(Wp + 4096);
    const half8* wv = (const half8*)(Wp + 8192);

    f32x4 accQ[4], accK[4], accV[4];
#pragma unroll
    for (int dt = 0; dt < 4; ++dt) {
        const int fi = (dt * 16 + ql) * 8;
        f32x4 z = {0.f, 0.f, 0.f, 0.f};
        accQ[dt] = MFMA16(af0, wq[fi + g], z);
        accQ[dt] = MFMA16(af1, wq[fi + 4 + g], accQ[dt]);
        accK[dt] = MFMA16(af0, wk[fi + g], z);
        accK[dt] = MFMA16(af1, wk[fi + 4 + g], accK[dt]);
        accV[dt] = MFMA16(af0, wv[fi + g], z);
        accV[dt] = MFMA16(af1, wv[fi + 4 + g], accV[dt]);
    }

#pragma unroll
    for (int dt = 0; dt < 4; ++dt)
#pragma unroll
        for (int r = 0; r < 4; ++r) {
            const int trow = rowbase + 4 * g + r;
            const int tt   = trow & (T_ - 1);
            const int d    = dt * 16 + ql;
            Qh[(size_t)trow * 64 + d] = (_Float16)(accQ[dt][r] * LOG2E);
            {
                const int kt = tt >> 4, qr = tt & 15;
                const int p  = ((d >> 5) << 2) | ((d >> 3) & 3);
                Kf[(((size_t)b * 128 + kt) * 8 + p) * 128 + qr * 8 + (d & 7)]
                    = (_Float16)accK[dt][r];
            }
            {
                const int kt5 = tt >> 5, c = tt & 31;
                Vf[(((((size_t)b * 64 + kt5) * 4 + dt) * 16 + ql) * 4 + (c >> 3)) * 8 + (c & 7)]
                    = (_Float16)accV[dt][r];
            }
        }
}

// pack two fp32 -> fp16x2 in a u32
__device__ inline unsigned pkh(float a, float b)
{
    union { _Float16 h[2]; unsigned u; } z;
    z.h[0] = (_Float16)a;
    z.h[1] = (_Float16)b;
    return z.u;
}

struct QTile {
    half8 qf0, qf1;
    f32x4 acc[4];
    float m, lsum;
};

// One q-tile's QK^T -> online softmax -> PV for a 32-key chunk (R6-verified).
__device__ __forceinline__ void process_tile(
    QTile& t,
    const half8 k0lo, const half8 k0hi, const half8 k1lo, const half8 k1hi,
    const half8 v0, const half8 v1, const half8 v2, const half8 v3,
    const int L0, const int L1, const bool hi,
    const int R0, const int R1, const int R2, const int R3)
{
    f32x4 s0 = {0.f, 0.f, 0.f, 0.f};
    f32x4 s1 = {0.f, 0.f, 0.f, 0.f};
    s0 = MFMA16(k0lo, t.qf0, s0);
    s0 = MFMA16(k0hi, t.qf1, s0);
    s1 = MFMA16(k1lo, t.qf0, s1);
    s1 = MFMA16(k1hi, t.qf1, s1);

    float p0 = s0[0], p1 = s0[1], p2 = s0[2], p3 = s0[3];
    float p4 = s1[0], p5 = s1[1], p6 = s1[2], p7 = s1[3];

    float pm = fmaxf(fmaxf(fmaxf(p0, p1), fmaxf(p2, p3)),
                     fmaxf(fmaxf(p4, p5), fmaxf(p6, p7)));
    pm = fmaxf(pm, __shfl_xor(pm, 16));
    pm = fmaxf(pm, __shfl_xor(pm, 32));

    float fac = 1.0f;
    if (__any(pm - t.m > 8.0f)) {              // defer-max (T13)
        const float mnew = fmaxf(t.m, pm);
        fac = exp2f(t.m - mnew);
        t.m = mnew;
        const float f0 = __shfl(fac, R0);
        const float f1 = __shfl(fac, R1);
        const float f2 = __shfl(fac, R2);
        const float f3 = __shfl(fac, R3);
#pragma unroll
        for (int dt = 0; dt < 4; ++dt) {
            t.acc[dt][0] *= f0; t.acc[dt][1] *= f1;
            t.acc[dt][2] *= f2; t.acc[dt][3] *= f3;
        }
    }

    p0 = exp2f(p0 - t.m); p1 = exp2f(p1 - t.m);
    p2 = exp2f(p2 - t.m); p3 = exp2f(p3 - t.m);
    p4 = exp2f(p4 - t.m); p5 = exp2f(p5 - t.m);
    p6 = exp2f(p6 - t.m); p7 = exp2f(p7 - t.m);

    float psum = ((p0 + p1) + (p2 + p3)) + ((p4 + p5) + (p6 + p7));
    psum += __shfl_xor(psum, 16);
    psum += __shfl_xor(psum, 32);
    t.lsum = t.lsum * fac + psum;

    const unsigned t0a = pkh(p0, p1), t0b = pkh(p2, p3);
    const unsigned t1a = pkh(p4, p5), t1b = pkh(p6, p7);
    const unsigned x0a = (unsigned)__shfl((int)t0a, L0);
    const unsigned x1a = (unsigned)__shfl((int)t1a, L0);
    const unsigned x0b = (unsigned)__shfl((int)t0b, L0);
    const unsigned x1b = (unsigned)__shfl((int)t1b, L0);
    const unsigned y0a = (unsigned)__shfl((int)t0a, L1);
    const unsigned y1a = (unsigned)__shfl((int)t1a, L1);
    const unsigned y0b = (unsigned)__shfl((int)t0b, L1);
    const unsigned y1b = (unsigned)__shfl((int)t1b, L1);
    union { unsigned u[4]; half8 v; } pa;
    pa.u[0] = hi ? x1a : x0a;
    pa.u[1] = hi ? x1b : x0b;
    pa.u[2] = hi ? y1a : y0a;
    pa.u[3] = hi ? y1b : y0b;

    t.acc[0] = MFMA16(pa.v, v0, t.acc[0]);
    t.acc[1] = MFMA16(pa.v, v1, t.acc[1]);
    t.acc[2] = MFMA16(pa.v, v2, t.acc[2]);
    t.acc[3] = MFMA16(pa.v, v3, t.acc[3]);
}

// ---------------------------------------------------------------------------
// Kernel 2: flash attention. Grid = 256 blocks x 8 waves (512 thr).
// b = blk&7 (XCD affinity), block owns 64 q-rows. Each wave owns ALL FOUR
// 16-row q-tiles and one 256-key split (ks = wid, 8 iters of 32 keys):
// 8 coalesced 1KB loads now feed 32 MFMA (4x work per load vs R4; per-CU
// wave-iters 128 -> 64). 8 partials per q-row merged in LDS.
// ---------------------------------------------------------------------------
__global__ __launch_bounds__(512, 2) void attn_kernel(
    const _Float16* __restrict__ Qh, const _Float16* __restrict__ Kf,
    const _Float16* __restrict__ Vf, const float* __restrict__ F,
    float* __restrict__ out)
{
    __shared__ float Ol[8][64][68];    // 139 KB: [split][row][d]
    __shared__ float Ml[8][64];
    __shared__ float Ll[8][64];

    const int lane = threadIdx.x & 63;
    const int wid  = threadIdx.x >> 6;           // 0..7 = key-split
    const int blk  = blockIdx.x;                 // 0..255
    const int b    = blk & 7;                    // XCD-affine batch
    const int tile = blk >> 3;                   // 0..31
    const int ql = lane & 15;
    const int g  = lane >> 4;

    const _Float16* Qbb = Qh + (size_t)b * T_ * 64;
    const half8* KfB = (const half8*)Kf + (size_t)b * 16384;  // 128 tiles * 128
    const half8* VfB = (const half8*)Vf + (size_t)b * 16384;  // 64 tiles * 256

    QTile tA, tB, tC, tD;
    {
        const int qb = (tile << 6);
        const half8* qpA = (const half8*)(Qbb + (qb +      ql) * 64);
        const half8* qpB = (const half8*)(Qbb + (qb + 16 + ql) * 64);
        const half8* qpC = (const half8*)(Qbb + (qb + 32 + ql) * 64);
        const half8* qpD = (const half8*)(Qbb + (qb + 48 + ql) * 64);
        tA.qf0 = qpA[g];  tA.qf1 = qpA[4 + g];
        tB.qf0 = qpB[g];  tB.qf1 = qpB[4 + g];
        tC.qf0 = qpC[g];  tC.qf1 = qpC[4 + g];
        tD.qf0 = qpD[g];  tD.qf1 = qpD[4 + g];
    }
#pragma unroll
    for (int dt = 0; dt < 4; ++dt) {
        tA.acc[dt] = f32x4{0.f, 0.f, 0.f, 0.f};
        tB.acc[dt] = f32x4{0.f, 0.f, 0.f, 0.f};
        tC.acc[dt] = f32x4{0.f, 0.f, 0.f, 0.f};
        tD.acc[dt] = f32x4{0.f, 0.f, 0.f, 0.f};
    }
    tA.m = -1e30f; tA.lsum = 0.f;
    tB.m = -1e30f; tB.lsum = 0.f;
    tC.m = -1e30f; tC.lsum = 0.f;
    tD.m = -1e30f; tD.lsum = 0.f;

    const int L0 = ql | (((2 * g) & 3) << 4);
    const int L1 = ql | (((2 * g + 1) & 3) << 4);
    const bool hi = (g >= 2);
    const int R0 = (lane & 48) | (4 * g + 0);
    const int R1 = (lane & 48) | (4 * g + 1);
    const int R2 = (lane & 48) | (4 * g + 2);
    const int R3 = (lane & 48) | (4 * g + 3);

    const int kb0 = wid << 8;                    // 256 keys per split
    for (int kb = kb0; kb < kb0 + 256; kb += 32) {
        const half8* ktb = KfB + (size_t)(kb >> 4) * 128;
        const half8 k0lo = ktb[g * 16 + ql];
        const half8 k0hi = ktb[(4 + g) * 16 + ql];
        const half8 k1lo = ktb[128 + g * 16 + ql];
        const half8 k1hi = ktb[128 + (4 + g) * 16 + ql];
        const half8* vtb = VfB + (size_t)(kb >> 5) * 256;
        const half8 v0 = vtb[(0 * 16 + ql) * 4 + g];
        const half8 v1 = vtb[(1 * 16 + ql) * 4 + g];
        const half8 v2 = vtb[(2 * 16 + ql) * 4 + g];
        const half8 v3 = vtb[(3 * 16 + ql) * 4 + g];

        process_tile(tA, k0lo, k0hi, k1lo, k1hi, v0, v1, v2, v3,
                     L0, L1, hi, R0, R1, R2, R3);
        process_tile(tB, k0lo, k0hi, k1lo, k1hi, v0, v1, v2, v3,
                     L0, L1, hi, R0, R1, R2, R3);
        process_tile(tC, k0lo, k0hi, k1lo, k1hi, v0, v1, v2, v3,
                     L0, L1, hi, R0, R1, R2, R3);
        process_tile(tD, k0lo, k0hi, k1lo, k1hi, v0, v1, v2, v3,
                     L0, L1, hi, R0, R1, R2, R3);
    }

    // ---- write partials to LDS: rows 0..15=A, 16..31=B, 32..47=C, 48..63=D
#pragma unroll
    for (int dt = 0; dt < 4; ++dt)
#pragma unroll
        for (int r = 0; r < 4; ++r) {
            Ol[wid][     4 * g + r][dt * 16 + ql] = tA.acc[dt][r];
            Ol[wid][16 + 4 * g + r][dt * 16 + ql] = tB.acc[dt][r];
            Ol[wid][32 + 4 * g + r][dt * 16 + ql] = tC.acc[dt][r];
            Ol[wid][48 + 4 * g + r][dt * 16 + ql] = tD.acc[dt][r];
        }
    if (g == 0) {
        Ml[wid][     ql] = tA.m;  Ll[wid][     ql] = tA.lsum;
        Ml[wid][16 + ql] = tB.m;  Ll[wid][16 + ql] = tB.lsum;
        Ml[wid][32 + ql] = tC.m;  Ll[wid][32 + ql] = tC.lsum;
        Ml[wid][48 + ql] = tD.m;  Ll[wid][48 + ql] = tD.lsum;
    }
    __syncthreads();

    // ---- combine 8 key-splits; 512 threads, one (row, 8-col chunk) each ----
    const int tid = threadIdx.x;
    const int qq  = tid >> 3;                    // 0..63 row within block
    const int d0  = (tid & 7) * 8;

    float mm[8], lv[8];
#pragma unroll
    for (int s = 0; s < 8; ++s) {
        mm[s] = Ml[s][qq];
        lv[s] = Ll[s][qq];
    }
    float ms = mm[0];
#pragma unroll
    for (int s = 1; s < 8; ++s) ms = fmaxf(ms, mm[s]);
    float lt = 0.f;
    f32x4 oa = {0.f, 0.f, 0.f, 0.f};
    f32x4 ob2 = {0.f, 0.f, 0.f, 0.f};
#pragma unroll
    for (int s = 0; s < 8; ++s) {
        const float sc = exp2f(mm[s] - ms);
        lt += lv[s] * sc;
        oa  += *(const f32x4*)(&Ol[s][qq][d0])     * sc;
        ob2 += *(const f32x4*)(&Ol[s][qq][d0 + 4]) * sc;
    }
    const float inv = 1.0f / lt;
    const size_t grow = (size_t)b * T_ + (tile << 6) + qq;
    const f32x4 fr0 = *(const f32x4*)(F + grow * 64 + d0);
    const f32x4 fr1 = *(const f32x4*)(F + grow * 64 + d0 + 4);
    *(f32x4*)(out + grow * 64 + d0)     = oa * inv + fr0;
    *(f32x4*)(out + grow * 64 + d0 + 4) = ob2 * inv + fr1;
}

extern "C" void kernel_launch(void* const* d_in, const int* in_sizes, int n_in,
                              void* d_out, int out_size, void* d_ws, size_t ws_size,
                              hipStream_t stream)
{
    const float* F  = (const float*)d_in[0];
    const float* WM = (const float*)d_in[1];
    const float* WN = (const float*)d_in[2];
    const float* WV = (const float*)d_in[3];
    float* out = (float*)d_out;

    const size_t proj_bytes = (size_t)B_ * T_ * 64 * sizeof(_Float16); // 2 MB
    char* ws = (char*)d_ws;
    _Float16* Qh = (_Float16*)(ws);
    _Float16* Kf = (_Float16*)(ws + proj_bytes);
    _Float16* Vf = (_Float16*)(ws + 2 * proj_bytes);
    _Float16* Wp = (_Float16*)(ws + 3 * proj_bytes);  // 3*64*64 f16 = 24 KB

    hipLaunchKernelGGL(prepack_kernel, dim3(48), dim3(256), 0, stream,
                       WM, WN, WV, Wp);
    hipLaunchKernelGGL(proj_kernel, dim3(B_ * T_ / 64), dim3(256), 0, stream,
                       F, Wp, Qh, Kf, Vf);
    hipLaunchKernelGGL(attn_kernel, dim3(B_ * T_ / 64), dim3(512), 0, stream,
                       Qh, Kf, Vf, F, out);
}

// Round 8
// 43.394 us; speedup vs baseline: 1.0100x; 1.0100x over previous
//
#include <hip/hip_runtime.h>
#include <hip/hip_bf16.h>

// Problem constants (fixed by reference): B=8, T=2048, C=64
#define B_ 8
#define T_ 2048
#define LOG2E 1.4426950408889634f

typedef _Float16 half8 __attribute__((ext_vector_type(8)));
typedef float f32x4 __attribute__((ext_vector_type(4)));

#define MFMA16(A, Bv, Cv) __builtin_amdgcn_mfma_f32_16x16x32_f16((A), (Bv), (Cv), 0, 0, 0)

// ---------------------------------------------------------------------------
// Kernel 0: pre-pack weights. W [k][d] fp32 -> Wp [mat][d][k] f16.
// ---------------------------------------------------------------------------
__global__ __launch_bounds__(256) void prepack_kernel(
    const float* __restrict__ WM, const float* __restrict__ WN,
    const float* __restrict__ WV, _Float16* __restrict__ Wp)
{
    const int idx = blockIdx.x * 256 + threadIdx.x;   // [0, 12288)
    const int m = idx >> 12;
    const int r = idx & 4095;
    const int d = r >> 6;
    const int k = r & 63;
    const float* W = (m == 0) ? WM : (m == 1) ? WN : WV;
    Wp[m * 4096 + d * 64 + k] = (_Float16)W[k * 64 + d];
}

// ---------------------------------------------------------------------------
// Kernel 1: MFMA projections -> fragment-major K/V layouts (R6-verified
// formulas). Restructured for TLP: 1024 blocks x 4 waves; block = 16 rows
// (XCD-affine: b = blk&7), wave = one 16-col dt-slice (6 MFMA).
// Grid 1024 -> 4 blocks/CU = 4 waves/SIMD (was 1).
// ---------------------------------------------------------------------------
__global__ __launch_bounds__(256) void proj_kernel(
    const float* __restrict__ F, const _Float16* __restrict__ Wp,
    _Float16* __restrict__ Qh, _Float16* __restrict__ Kf,
    _Float16* __restrict__ Vf)
{
    const int lane = threadIdx.x & 63;
    const int dt   = threadIdx.x >> 6;            // 0..3 = d-tile
    const int ql = lane & 15;
    const int g  = lane >> 4;
    const int blk = blockIdx.x;                   // 0..1023
    const int b   = blk & 7;                      // XCD-affine batch
    const int rt  = blk >> 3;                     // 0..127 row-tile in batch
    const int rowbase = b * T_ + rt * 16;

    const float* fr = F + (size_t)(rowbase + ql) * 64;
    union { f32x4 v[2]; float s[8]; } fa0, fa1;
    fa0.v[0] = *(const f32x4*)(fr + 8 * g);
    fa0.v[1] = *(const f32x4*)(fr + 8 * g + 4);
    fa1.v[0] = *(const f32x4*)(fr + 32 + 8 * g);
    fa1.v[1] = *(const f32x4*)(fr + 32 + 8 * g + 4);
    half8 af0, af1;
#pragma unroll
    for (int j = 0; j < 8; ++j) {
        af0[j] = (_Float16)fa0.s[j];
        af1[j] = (_Float16)fa1.s[j];
    }

    const half8* wq = (const half8*)(Wp);
    const half8* wk = (const half8*)(Wp + 4096);
    const half8* wv = (const half8*)(Wp + 8192);

    const int fi = (dt * 16 + ql) * 8;
    f32x4 z = {0.f, 0.f, 0.f, 0.f};
    f32x4 accQ = MFMA16(af0, wq[fi + g], z);
    accQ = MFMA16(af1, wq[fi + 4 + g], accQ);
    f32x4 accK = MFMA16(af0, wk[fi + g], z);
    accK = MFMA16(af1, wk[fi + 4 + g], accK);
    f32x4 accV = MFMA16(af0, wv[fi + g], z);
    accV = MFMA16(af1, wv[fi + 4 + g], accV);

#pragma unroll
    for (int r = 0; r < 4; ++r) {
        const int trow = rowbase + 4 * g + r;
        const int tt   = trow & (T_ - 1);
        const int d    = dt * 16 + ql;
        Qh[(size_t)trow * 64 + d] = (_Float16)(accQ[r] * LOG2E);
        {
            const int kt = tt >> 4, qr = tt & 15;
            const int p  = ((d >> 5) << 2) | ((d >> 3) & 3);
            Kf[(((size_t)b * 128 + kt) * 8 + p) * 128 + qr * 8 + (d & 7)]
                = (_Float16)accK[r];
        }
        {
            const int kt5 = tt >> 5, c = tt & 31;
            Vf[(((((size_t)b * 64 + kt5) * 4 + dt) * 16 + ql) * 4 + (c >> 3)) * 8 + (c & 7)]
                = (_Float16)accV[r];
        }
    }
}

// pack two fp32 -> fp16x2 in a u32
__device__ inline unsigned pkh(float a, float b)
{
    union { _Float16 h[2]; unsigned u; } z;
    z.h[0] = (_Float16)a;
    z.h[1] = (_Float16)b;
    return z.u;
}

struct QTile {
    half8 qf0, qf1;
    f32x4 acc[4];
    float m, lsum;
};

// One q-tile's QK^T -> online softmax -> PV for a 32-key chunk (R6-verified).
__device__ __forceinline__ void process_tile(
    QTile& t,
    const half8 k0lo, const half8 k0hi, const half8 k1lo, const half8 k1hi,
    const half8 v0, const half8 v1, const half8 v2, const half8 v3,
    const int L0, const int L1, const bool hi,
    const int R0, const int R1, const int R2, const int R3)
{
    f32x4 s0 = {0.f, 0.f, 0.f, 0.f};
    f32x4 s1 = {0.f, 0.f, 0.f, 0.f};
    s0 = MFMA16(k0lo, t.qf0, s0);
    s0 = MFMA16(k0hi, t.qf1, s0);
    s1 = MFMA16(k1lo, t.qf0, s1);
    s1 = MFMA16(k1hi, t.qf1, s1);

    float p0 = s0[0], p1 = s0[1], p2 = s0[2], p3 = s0[3];
    float p4 = s1[0], p5 = s1[1], p6 = s1[2], p7 = s1[3];

    float pm = fmaxf(fmaxf(fmaxf(p0, p1), fmaxf(p2, p3)),
                     fmaxf(fmaxf(p4, p5), fmaxf(p6, p7)));
    pm = fmaxf(pm, __shfl_xor(pm, 16));
    pm = fmaxf(pm, __shfl_xor(pm, 32));

    float fac = 1.0f;
    if (__any(pm - t.m > 8.0f)) {              // defer-max (T13)
        const float mnew = fmaxf(t.m, pm);
        fac = exp2f(t.m - mnew);
        t.m = mnew;
        const float f0 = __shfl(fac, R0);
        const float f1 = __shfl(fac, R1);
        const float f2 = __shfl(fac, R2);
        const float f3 = __shfl(fac, R3);
#pragma unroll
        for (int dt = 0; dt < 4; ++dt) {
            t.acc[dt][0] *= f0; t.acc[dt][1] *= f1;
            t.acc[dt][2] *= f2; t.acc[dt][3] *= f3;
        }
    }

    p0 = exp2f(p0 - t.m); p1 = exp2f(p1 - t.m);
    p2 = exp2f(p2 - t.m); p3 = exp2f(p3 - t.m);
    p4 = exp2f(p4 - t.m); p5 = exp2f(p5 - t.m);
    p6 = exp2f(p6 - t.m); p7 = exp2f(p7 - t.m);

    float psum = ((p0 + p1) + (p2 + p3)) + ((p4 + p5) + (p6 + p7));
    psum += __shfl_xor(psum, 16);
    psum += __shfl_xor(psum, 32);
    t.lsum = t.lsum * fac + psum;

    const unsigned t0a = pkh(p0, p1), t0b = pkh(p2, p3);
    const unsigned t1a = pkh(p4, p5), t1b = pkh(p6, p7);
    const unsigned x0a = (unsigned)__shfl((int)t0a, L0);
    const unsigned x1a = (unsigned)__shfl((int)t1a, L0);
    const unsigned x0b = (unsigned)__shfl((int)t0b, L0);
    const unsigned x1b = (unsigned)__shfl((int)t1b, L0);
    const unsigned y0a = (unsigned)__shfl((int)t0a, L1);
    const unsigned y1a = (unsigned)__shfl((int)t1a, L1);
    const unsigned y0b = (unsigned)__shfl((int)t0b, L1);
    const unsigned y1b = (unsigned)__shfl((int)t1b, L1);
    union { unsigned u[4]; half8 v; } pa;
    pa.u[0] = hi ? x1a : x0a;
    pa.u[1] = hi ? x1b : x0b;
    pa.u[2] = hi ? y1a : y0a;
    pa.u[3] = hi ? y1b : y0b;

    t.acc[0] = MFMA16(pa.v, v0, t.acc[0]);
    t.acc[1] = MFMA16(pa.v, v1, t.acc[1]);
    t.acc[2] = MFMA16(pa.v, v2, t.acc[2]);
    t.acc[3] = MFMA16(pa.v, v3, t.acc[3]);
}

// ---------------------------------------------------------------------------
// Kernel 2: flash attention. Grid = 1024 blocks x 4 waves (256 thr).
// b = blk&7 (XCD affinity); block = ONE 16-row q-tile over all 2048 keys;
// wave = 512-key split (wid = ks). 4 blocks/CU -> 4 waves/SIMD (2x R6/R7)
// to overlap the per-tile softmax dependency chain. LDS merge of 4 partials.
// ---------------------------------------------------------------------------
__global__ __launch_bounds__(256) void attn_kernel(
    const _Float16* __restrict__ Qh, const _Float16* __restrict__ Kf,
    const _Float16* __restrict__ Vf, const float* __restrict__ F,
    float* __restrict__ out)
{
    __shared__ float Ol[4][16][68];    // ~17.4 KB
    __shared__ float Ml[4][16];
    __shared__ float Ll[4][16];

    const int lane = threadIdx.x & 63;
    const int wid  = threadIdx.x >> 6;           // 0..3 = key-split
    const int blk  = blockIdx.x;                 // 0..1023
    const int b    = blk & 7;                    // XCD-affine batch
    const int tile = blk >> 3;                   // 0..127 q-tile in batch
    const int ql = lane & 15;
    const int g  = lane >> 4;

    const _Float16* Qbb = Qh + (size_t)b * T_ * 64;
    const half8* KfB = (const half8*)Kf + (size_t)b * 16384;  // 128 tiles * 128
    const half8* VfB = (const half8*)Vf + (size_t)b * 16384;  // 64 tiles * 256

    QTile t;
    {
        const half8* qp = (const half8*)(Qbb + (tile * 16 + ql) * 64);
        t.qf0 = qp[g];
        t.qf1 = qp[4 + g];
    }
#pragma unroll
    for (int dt = 0; dt < 4; ++dt) t.acc[dt] = f32x4{0.f, 0.f, 0.f, 0.f};
    t.m = -1e30f;
    t.lsum = 0.f;

    const int L0 = ql | (((2 * g) & 3) << 4);
    const int L1 = ql | (((2 * g + 1) & 3) << 4);
    const bool hi = (g >= 2);
    const int R0 = (lane & 48) | (4 * g + 0);
    const int R1 = (lane & 48) | (4 * g + 1);
    const int R2 = (lane & 48) | (4 * g + 2);
    const int R3 = (lane & 48) | (4 * g + 3);

    const int kb0 = wid << 9;                    // 512 keys per split
    for (int kb = kb0; kb < kb0 + 512; kb += 32) {
        const half8* ktb = KfB + (size_t)(kb >> 4) * 128;
        const half8 k0lo = ktb[g * 16 + ql];
        const half8 k0hi = ktb[(4 + g) * 16 + ql];
        const half8 k1lo = ktb[128 + g * 16 + ql];
        const half8 k1hi = ktb[128 + (4 + g) * 16 + ql];
        const half8* vtb = VfB + (size_t)(kb >> 5) * 256;
        const half8 v0 = vtb[(0 * 16 + ql) * 4 + g];
        const half8 v1 = vtb[(1 * 16 + ql) * 4 + g];
        const half8 v2 = vtb[(2 * 16 + ql) * 4 + g];
        const half8 v3 = vtb[(3 * 16 + ql) * 4 + g];

        process_tile(t, k0lo, k0hi, k1lo, k1hi, v0, v1, v2, v3,
                     L0, L1, hi, R0, R1, R2, R3);
    }

    // ---- write partials to LDS ----
#pragma unroll
    for (int dt = 0; dt < 4; ++dt)
#pragma unroll
        for (int r = 0; r < 4; ++r)
            Ol[wid][4 * g + r][dt * 16 + ql] = t.acc[dt][r];
    if (g == 0) {
        Ml[wid][ql] = t.m;
        Ll[wid][ql] = t.lsum;
    }
    __syncthreads();

    // ---- combine 4 key-splits; 256 threads, one (row, 4-col chunk) each ----
    const int tid = threadIdx.x;
    const int row = tid >> 4;                    // 0..15
    const int d0  = (tid & 15) * 4;

    float mm[4], lv[4];
#pragma unroll
    for (int s = 0; s < 4; ++s) {
        mm[s] = Ml[s][row];
        lv[s] = Ll[s][row];
    }
    const float ms = fmaxf(fmaxf(mm[0], mm[1]), fmaxf(mm[2], mm[3]));
    float lt = 0.f;
    f32x4 o = {0.f, 0.f, 0.f, 0.f};
#pragma unroll
    for (int s = 0; s < 4; ++s) {
        const float sc = exp2f(mm[s] - ms);
        lt += lv[s] * sc;
        o += *(const f32x4*)(&Ol[s][row][d0]) * sc;
    }
    const float inv = 1.0f / lt;
    const size_t grow = (size_t)b * T_ + tile * 16 + row;
    const f32x4 fres = *(const f32x4*)(F + grow * 64 + d0);
    *(f32x4*)(out + grow * 64 + d0) = o * inv + fres;
}

extern "C" void kernel_launch(void* const* d_in, const int* in_sizes, int n_in,
                              void* d_out, int out_size, void* d_ws, size_t ws_size,
                              hipStream_t stream)
{
    const float* F  = (const float*)d_in[0];
    const float* WM = (const float*)d_in[1];
    const float* WN = (const float*)d_in[2];
    const float* WV = (const float*)d_in[3];
    float* out = (float*)d_out;

    const size_t proj_bytes = (size_t)B_ * T_ * 64 * sizeof(_Float16); // 2 MB
    char* ws = (char*)d_ws;
    _Float16* Qh = (_Float16*)(ws);
    _Float16* Kf = (_Float16*)(ws + proj_bytes);
    _Float16* Vf = (_Float16*)(ws + 2 * proj_bytes);
    _Float16* Wp = (_Float16*)(ws + 3 * proj_bytes);  // 3*64*64 f16 = 24 KB

    hipLaunchKernelGGL(prepack_kernel, dim3(48), dim3(256), 0, stream,
                       WM, WN, WV, Wp);
    hipLaunchKernelGGL(proj_kernel, dim3(B_ * T_ / 16), dim3(256), 0, stream,
                       F, Wp, Qh, Kf, Vf);
    hipLaunchKernelGGL(attn_kernel, dim3(B_ * T_ / 16), dim3(256), 0, stream,
                       Qh, Kf, Vf, F, out);
}

// Round 9
// 40.067 us; speedup vs baseline: 1.0939x; 1.0830x over previous
//
#include <hip/hip_runtime.h>
#include <hip/hip_bf16.h>

// Problem constants (fixed by reference): B=8, T=2048, C=64
#define B_ 8
#define T_ 2048
#define LOG2E 1.4426950408889634f

typedef _Float16 half8 __attribute__((ext_vector_type(8)));
typedef float f32x4 __attribute__((ext_vector_type(4)));

#define MFMA16(A, Bv, Cv) __builtin_amdgcn_mfma_f32_16x16x32_f16((A), (Bv), (Cv), 0, 0, 0)

// ---------------------------------------------------------------------------
// Kernel 0: pre-pack weights. W [k][d] fp32 -> Wp [mat][d][k] f16.
// ---------------------------------------------------------------------------
__global__ __launch_bounds__(256) void prepack_kernel(
    const float* __restrict__ WM, const float* __restrict__ WN,
    const float* __restrict__ WV, _Float16* __restrict__ Wp)
{
    const int idx = blockIdx.x * 256 + threadIdx.x;   // [0, 12288)
    const int m = idx >> 12;
    const int r = idx & 4095;
    const int d = r >> 6;
    const int k = r & 63;
    const float* W = (m == 0) ? WM : (m == 1) ? WN : WV;
    Wp[m * 4096 + d * 64 + k] = (_Float16)W[k * 64 + d];
}

// ---------------------------------------------------------------------------
// Kernel 1: MFMA projections -> fragment-major K/V layouts.
// Q: row-major f16, pre-scaled by LOG2E.
// Kf: per-batch 16-key tiles [kt][d>>3][t&15][d&7]  (tile = 128 half8).
// Vf: per-batch 32-key tiles [kt5][dt][d&15][pos>>3][pos&7] (tile = 256 half8)
//     where pos = sigma^-1(key): key c -> pos = c<16 ? 8*(c>>2)+(c&3)
//                                              : 8*((c&15)>>2)+4+(c&3).
//     This bakes the PV A-fragment's positional key map (lane group g holds
//     keys {4g..4g+3, 16+4g..16+4g+3} at slots 8g..8g+7) into V, so attn
//     packs P directly from registers with ZERO cross-lane ops.
// ---------------------------------------------------------------------------
__global__ __launch_bounds__(256) void proj_kernel(
    const float* __restrict__ F, const _Float16* __restrict__ Wp,
    _Float16* __restrict__ Qh, _Float16* __restrict__ Kf,
    _Float16* __restrict__ Vf)
{
    const int lane = threadIdx.x & 63;
    const int dt   = threadIdx.x >> 6;            // 0..3 = d-tile
    const int ql = lane & 15;
    const int g  = lane >> 4;
    const int blk = blockIdx.x;                   // 0..1023
    const int b   = blk & 7;                      // XCD-affine batch
    const int rt  = blk >> 3;                     // 0..127 row-tile in batch
    const int rowbase = b * T_ + rt * 16;

    const float* fr = F + (size_t)(rowbase + ql) * 64;
    union { f32x4 v[2]; float s[8]; } fa0, fa1;
    fa0.v[0] = *(const f32x4*)(fr + 8 * g);
    fa0.v[1] = *(const f32x4*)(fr + 8 * g + 4);
    fa1.v[0] = *(const f32x4*)(fr + 32 + 8 * g);
    fa1.v[1] = *(const f32x4*)(fr + 32 + 8 * g + 4);
    half8 af0, af1;
#pragma unroll
    for (int j = 0; j < 8; ++j) {
        af0[j] = (_Float16)fa0.s[j];
        af1[j] = (_Float16)fa1.s[j];
    }

    const half8* wq = (const half8*)(Wp);
    const half8* wk = (const half8*)(Wp + 4096);
    const half8* wv = (const half8*)(Wp + 8192);

    const int fi = (dt * 16 + ql) * 8;
    f32x4 z = {0.f, 0.f, 0.f, 0.f};
    f32x4 accQ = MFMA16(af0, wq[fi + g], z);
    accQ = MFMA16(af1, wq[fi + 4 + g], accQ);
    f32x4 accK = MFMA16(af0, wk[fi + g], z);
    accK = MFMA16(af1, wk[fi + 4 + g], accK);
    f32x4 accV = MFMA16(af0, wv[fi + g], z);
    accV = MFMA16(af1, wv[fi + 4 + g], accV);

#pragma unroll
    for (int r = 0; r < 4; ++r) {
        const int trow = rowbase + 4 * g + r;
        const int tt   = trow & (T_ - 1);
        const int d    = dt * 16 + ql;
        Qh[(size_t)trow * 64 + d] = (_Float16)(accQ[r] * LOG2E);
        {
            const int kt = tt >> 4, qr = tt & 15;
            const int p  = ((d >> 5) << 2) | ((d >> 3) & 3);
            Kf[(((size_t)b * 128 + kt) * 8 + p) * 128 + qr * 8 + (d & 7)]
                = (_Float16)accK[r];
        }
        {
            const int kt5 = tt >> 5, c = tt & 31;
            const int cp  = (c < 16) ? (8 * (c >> 2) + (c & 3))
                                     : (8 * ((c & 15) >> 2) + 4 + (c & 3));
            Vf[(((((size_t)b * 64 + kt5) * 4 + dt) * 16 + ql) * 4 + (cp >> 3)) * 8 + (cp & 7)]
                = (_Float16)accV[r];
        }
    }
}

// pack two fp32 -> fp16x2 in a u32
__device__ inline unsigned pkh(float a, float b)
{
    union { _Float16 h[2]; unsigned u; } z;
    z.h[0] = (_Float16)a;
    z.h[1] = (_Float16)b;
    return z.u;
}

struct QTile {
    half8 qf0, qf1;
    f32x4 acc[4];
    float m, lsum;
};

// One q-tile's QK^T -> online softmax -> PV for a 32-key chunk.
// Steady state has ZERO cross-lane ops: lane-local max + T13 trigger
// (full reduce + rescale only when __any(pm - m > 8)), per-lane lsum
// partials (reduced once in the epilogue), and P packed directly into the
// PV A-fragment (V's key order is sigma-permuted in Vf to match).
__device__ __forceinline__ void process_tile(
    QTile& t,
    const half8 k0lo, const half8 k0hi, const half8 k1lo, const half8 k1hi,
    const half8 v0, const half8 v1, const half8 v2, const half8 v3,
    const int R0, const int R1, const int R2, const int R3)
{
    f32x4 s0 = {0.f, 0.f, 0.f, 0.f};
    f32x4 s1 = {0.f, 0.f, 0.f, 0.f};
    s0 = MFMA16(k0lo, t.qf0, s0);
    s0 = MFMA16(k0hi, t.qf1, s0);
    s1 = MFMA16(k1lo, t.qf0, s1);
    s1 = MFMA16(k1hi, t.qf1, s1);

    float p0 = s0[0], p1 = s0[1], p2 = s0[2], p3 = s0[3];
    float p4 = s1[0], p5 = s1[1], p6 = s1[2], p7 = s1[3];

    float pm = fmaxf(fmaxf(fmaxf(p0, p1), fmaxf(p2, p3)),
                     fmaxf(fmaxf(p4, p5), fmaxf(p6, p7)));

    if (__any(pm - t.m > 8.0f)) {              // T13 trigger (rare)
        pm = fmaxf(pm, __shfl_xor(pm, 16));
        pm = fmaxf(pm, __shfl_xor(pm, 32));
        const float mnew = fmaxf(t.m, pm);
        const float fac  = exp2f(t.m - mnew);   // per-q consistent
        t.m = mnew;
        t.lsum *= fac;
        const float f0 = __shfl(fac, R0);
        const float f1 = __shfl(fac, R1);
        const float f2 = __shfl(fac, R2);
        const float f3 = __shfl(fac, R3);
#pragma unroll
        for (int dt = 0; dt < 4; ++dt) {
            t.acc[dt][0] *= f0; t.acc[dt][1] *= f1;
            t.acc[dt][2] *= f2; t.acc[dt][3] *= f3;
        }
    }

    p0 = exp2f(p0 - t.m); p1 = exp2f(p1 - t.m);
    p2 = exp2f(p2 - t.m); p3 = exp2f(p3 - t.m);
    p4 = exp2f(p4 - t.m); p5 = exp2f(p5 - t.m);
    p6 = exp2f(p6 - t.m); p7 = exp2f(p7 - t.m);

    t.lsum += ((p0 + p1) + (p2 + p3)) + ((p4 + p5) + (p6 + p7));

    union { unsigned u[4]; half8 v; } pa;   // direct pack: slots 8g..8g+7
    pa.u[0] = pkh(p0, p1);
    pa.u[1] = pkh(p2, p3);
    pa.u[2] = pkh(p4, p5);
    pa.u[3] = pkh(p6, p7);

    t.acc[0] = MFMA16(pa.v, v0, t.acc[0]);
    t.acc[1] = MFMA16(pa.v, v1, t.acc[1]);
    t.acc[2] = MFMA16(pa.v, v2, t.acc[2]);
    t.acc[3] = MFMA16(pa.v, v3, t.acc[3]);
}

// ---------------------------------------------------------------------------
// Kernel 2: flash attention. Grid = 256 blocks x 8 waves (512 thr).
// b = blk&7 (XCD affinity), block owns 64 q-rows (best L2 amortization:
// K/V read once per 64 q). Wave = all four 16-row q-tiles x one 256-key
// split. Inner loop is cross-lane-free (see process_tile).
// ---------------------------------------------------------------------------
__global__ __launch_bounds__(512, 2) void attn_kernel(
    const _Float16* __restrict__ Qh, const _Float16* __restrict__ Kf,
    const _Float16* __restrict__ Vf, const float* __restrict__ F,
    float* __restrict__ out)
{
    __shared__ float Ol[8][64][68];    // 139 KB: [split][row][d]
    __shared__ float Ml[8][64];
    __shared__ float Ll[8][64];

    const int lane = threadIdx.x & 63;
    const int wid  = threadIdx.x >> 6;           // 0..7 = key-split
    const int blk  = blockIdx.x;                 // 0..255
    const int b    = blk & 7;                    // XCD-affine batch
    const int tile = blk >> 3;                   // 0..31
    const int ql = lane & 15;
    const int g  = lane >> 4;

    const _Float16* Qbb = Qh + (size_t)b * T_ * 64;
    const half8* KfB = (const half8*)Kf + (size_t)b * 16384;  // 128 tiles * 128
    const half8* VfB = (const half8*)Vf + (size_t)b * 16384;  // 64 tiles * 256

    QTile tA, tB, tC, tD;
    {
        const int qb = (tile << 6);
        const half8* qpA = (const half8*)(Qbb + (qb +      ql) * 64);
        const half8* qpB = (const half8*)(Qbb + (qb + 16 + ql) * 64);
        const half8* qpC = (const half8*)(Qbb + (qb + 32 + ql) * 64);
        const half8* qpD = (const half8*)(Qbb + (qb + 48 + ql) * 64);
        tA.qf0 = qpA[g];  tA.qf1 = qpA[4 + g];
        tB.qf0 = qpB[g];  tB.qf1 = qpB[4 + g];
        tC.qf0 = qpC[g];  tC.qf1 = qpC[4 + g];
        tD.qf0 = qpD[g];  tD.qf1 = qpD[4 + g];
    }
#pragma unroll
    for (int dt = 0; dt < 4; ++dt) {
        tA.acc[dt] = f32x4{0.f, 0.f, 0.f, 0.f};
        tB.acc[dt] = f32x4{0.f, 0.f, 0.f, 0.f};
        tC.acc[dt] = f32x4{0.f, 0.f, 0.f, 0.f};
        tD.acc[dt] = f32x4{0.f, 0.f, 0.f, 0.f};
    }
    tA.m = -1e30f; tA.lsum = 0.f;
    tB.m = -1e30f; tB.lsum = 0.f;
    tC.m = -1e30f; tC.lsum = 0.f;
    tD.m = -1e30f; tD.lsum = 0.f;

    const int R0 = (lane & 48) | (4 * g + 0);
    const int R1 = (lane & 48) | (4 * g + 1);
    const int R2 = (lane & 48) | (4 * g + 2);
    const int R3 = (lane & 48) | (4 * g + 3);

    const int kb0 = wid << 8;                    // 256 keys per split
    for (int kb = kb0; kb < kb0 + 256; kb += 32) {
        const half8* ktb = KfB + (size_t)(kb >> 4) * 128;
        const half8 k0lo = ktb[g * 16 + ql];
        const half8 k0hi = ktb[(4 + g) * 16 + ql];
        const half8 k1lo = ktb[128 + g * 16 + ql];
        const half8 k1hi = ktb[128 + (4 + g) * 16 + ql];
        const half8* vtb = VfB + (size_t)(kb >> 5) * 256;
        const half8 v0 = vtb[(0 * 16 + ql) * 4 + g];
        const half8 v1 = vtb[(1 * 16 + ql) * 4 + g];
        const half8 v2 = vtb[(2 * 16 + ql) * 4 + g];
        const half8 v3 = vtb[(3 * 16 + ql) * 4 + g];

        process_tile(tA, k0lo, k0hi, k1lo, k1hi, v0, v1, v2, v3, R0, R1, R2, R3);
        process_tile(tB, k0lo, k0hi, k1lo, k1hi, v0, v1, v2, v3, R0, R1, R2, R3);
        process_tile(tC, k0lo, k0hi, k1lo, k1hi, v0, v1, v2, v3, R0, R1, R2, R3);
        process_tile(tD, k0lo, k0hi, k1lo, k1hi, v0, v1, v2, v3, R0, R1, R2, R3);
    }

    // ---- reduce per-lane lsum partials across the 4 lane-groups ----
    float lsA = tA.lsum; lsA += __shfl_xor(lsA, 16); lsA += __shfl_xor(lsA, 32);
    float lsB = tB.lsum; lsB += __shfl_xor(lsB, 16); lsB += __shfl_xor(lsB, 32);
    float lsC = tC.lsum; lsC += __shfl_xor(lsC, 16); lsC += __shfl_xor(lsC, 32);
    float lsD = tD.lsum; lsD += __shfl_xor(lsD, 16); lsD += __shfl_xor(lsD, 32);

    // ---- write partials to LDS: rows 0..15=A, 16..31=B, 32..47=C, 48..63=D
#pragma unroll
    for (int dt = 0; dt < 4; ++dt)
#pragma unroll
        for (int r = 0; r < 4; ++r) {
            Ol[wid][     4 * g + r][dt * 16 + ql] = tA.acc[dt][r];
            Ol[wid][16 + 4 * g + r][dt * 16 + ql] = tB.acc[dt][r];
            Ol[wid][32 + 4 * g + r][dt * 16 + ql] = tC.acc[dt][r];
            Ol[wid][48 + 4 * g + r][dt * 16 + ql] = tD.acc[dt][r];
        }
    if (g == 0) {
        Ml[wid][     ql] = tA.m;  Ll[wid][     ql] = lsA;
        Ml[wid][16 + ql] = tB.m;  Ll[wid][16 + ql] = lsB;
        Ml[wid][32 + ql] = tC.m;  Ll[wid][32 + ql] = lsC;
        Ml[wid][48 + ql] = tD.m;  Ll[wid][48 + ql] = lsD;
    }
    __syncthreads();

    // ---- combine 8 key-splits; 512 threads, one (row, 8-col chunk) each ----
    const int tid = threadIdx.x;
    const int qq  = tid >> 3;                    // 0..63 row within block
    const int d0  = (tid & 7) * 8;

    float mm[8], lv[8];
#pragma unroll
    for (int s = 0; s < 8; ++s) {
        mm[s] = Ml[s][qq];
        lv[s] = Ll[s][qq];
    }
    float ms = mm[0];
#pragma unroll
    for (int s = 1; s < 8; ++s) ms = fmaxf(ms, mm[s]);
    float lt = 0.f;
    f32x4 oa = {0.f, 0.f, 0.f, 0.f};
    f32x4 ob2 = {0.f, 0.f, 0.f, 0.f};
#pragma unroll
    for (int s = 0; s < 8; ++s) {
        const float sc = exp2f(mm[s] - ms);
        lt += lv[s] * sc;
        oa  += *(const f32x4*)(&Ol[s][qq][d0])     * sc;
        ob2 += *(const f32x4*)(&Ol[s][qq][d0 + 4]) * sc;
    }
    const float inv = 1.0f / lt;
    const size_t grow = (size_t)b * T_ + (tile << 6) + qq;
    const f32x4 fr0 = *(const f32x4*)(F + grow * 64 + d0);
    const f32x4 fr1 = *(const f32x4*)(F + grow * 64 + d0 + 4);
    *(f32x4*)(out + grow * 64 + d0)     = oa * inv + fr0;
    *(f32x4*)(out + grow * 64 + d0 + 4) = ob2 * inv + fr1;
}

extern "C" void kernel_launch(void* const* d_in, const int* in_sizes, int n_in,
                              void* d_out, int out_size, void* d_ws, size_t ws_size,
                              hipStream_t stream)
{
    const float* F  = (const float*)d_in[0];
    const float* WM = (const float*)d_in[1];
    const float* WN = (const float*)d_in[2];
    const float* WV = (const float*)d_in[3];
    float* out = (float*)d_out;

    const size_t proj_bytes = (size_t)B_ * T_ * 64 * sizeof(_Float16); // 2 MB
    char* ws = (char*)d_ws;
    _Float16* Qh = (_Float16*)(ws);
    _Float16* Kf = (_Float16*)(ws + proj_bytes);
    _Float16* Vf = (_Float16*)(ws + 2 * proj_bytes);
    _Float16* Wp = (_Float16*)(ws + 3 * proj_bytes);  // 3*64*64 f16 = 24 KB

    hipLaunchKernelGGL(prepack_kernel, dim3(48), dim3(256), 0, stream,
                       WM, WN, WV, Wp);
    hipLaunchKernelGGL(proj_kernel, dim3(B_ * T_ / 16), dim3(256), 0, stream,
                       F, Wp, Qh, Kf, Vf);
    hipLaunchKernelGGL(attn_kernel, dim3(B_ * T_ / 64), dim3(512), 0, stream,
                       Qh, Kf, Vf, F, out);
}

// Round 10
// 34.247 us; speedup vs baseline: 1.2798x; 1.1699x over previous
//
#include <hip/hip_runtime.h>
#include <hip/hip_bf16.h>

// Problem constants (fixed by reference): B=8, T=2048, C=64
#define B_ 8
#define T_ 2048
#define LOG2E 1.4426950408889634f

typedef _Float16 half8 __attribute__((ext_vector_type(8)));
typedef float f32x4 __attribute__((ext_vector_type(4)));

#define MFMA16(A, Bv, Cv) __builtin_amdgcn_mfma_f32_16x16x32_f16((A), (Bv), (Cv), 0, 0, 0)

// native 2^x (base-2 domain throughout; |x| <= ~90 so no denorm/ovf issues)
__device__ inline float xexp2(float x)
{
    float r;
    asm("v_exp_f32 %0, %1" : "=v"(r) : "v"(x));
    return r;
}

// ---------------------------------------------------------------------------
// Kernel 0: pre-pack weights. W [k][d] fp32 -> Wp [mat][d][k] f16.
// ---------------------------------------------------------------------------
__global__ __launch_bounds__(256) void prepack_kernel(
    const float* __restrict__ WM, const float* __restrict__ WN,
    const float* __restrict__ WV, _Float16* __restrict__ Wp)
{
    const int idx = blockIdx.x * 256 + threadIdx.x;   // [0, 12288)
    const int m = idx >> 12;
    const int r = idx & 4095;
    const int d = r >> 6;
    const int k = r & 63;
    const float* W = (m == 0) ? WM : (m == 1) ? WN : WV;
    Wp[m * 4096 + d * 64 + k] = (_Float16)W[k * 64 + d];
}

// ---------------------------------------------------------------------------
// Kernel 1: MFMA projections -> fragment-major K/V layouts (R9-verified
// formulas; unions replaced by direct vector-element access).
// ---------------------------------------------------------------------------
__global__ __launch_bounds__(256) void proj_kernel(
    const float* __restrict__ F, const _Float16* __restrict__ Wp,
    _Float16* __restrict__ Qh, _Float16* __restrict__ Kf,
    _Float16* __restrict__ Vf)
{
    const int lane = threadIdx.x & 63;
    const int dt   = threadIdx.x >> 6;            // 0..3 = d-tile
    const int ql = lane & 15;
    const int g  = lane >> 4;
    const int blk = blockIdx.x;                   // 0..1023
    const int b   = blk & 7;                      // XCD-affine batch
    const int rt  = blk >> 3;                     // 0..127 row-tile in batch
    const int rowbase = b * T_ + rt * 16;

    const float* fr = F + (size_t)(rowbase + ql) * 64;
    const f32x4 v00 = *(const f32x4*)(fr + 8 * g);
    const f32x4 v01 = *(const f32x4*)(fr + 8 * g + 4);
    const f32x4 v10 = *(const f32x4*)(fr + 32 + 8 * g);
    const f32x4 v11 = *(const f32x4*)(fr + 32 + 8 * g + 4);
    half8 af0, af1;
#pragma unroll
    for (int j = 0; j < 4; ++j) {
        af0[j]     = (_Float16)v00[j];
        af0[4 + j] = (_Float16)v01[j];
        af1[j]     = (_Float16)v10[j];
        af1[4 + j] = (_Float16)v11[j];
    }

    const half8* wq = (const half8*)(Wp);
    const half8* wk = (const half8*)(Wp + 4096);
    const half8* wv = (const half8*)(Wp + 8192);

    const int fi = (dt * 16 + ql) * 8;
    f32x4 z = {0.f, 0.f, 0.f, 0.f};
    f32x4 accQ = MFMA16(af0, wq[fi + g], z);
    accQ = MFMA16(af1, wq[fi + 4 + g], accQ);
    f32x4 accK = MFMA16(af0, wk[fi + g], z);
    accK = MFMA16(af1, wk[fi + 4 + g], accK);
    f32x4 accV = MFMA16(af0, wv[fi + g], z);
    accV = MFMA16(af1, wv[fi + 4 + g], accV);

#pragma unroll
    for (int r = 0; r < 4; ++r) {
        const int trow = rowbase + 4 * g + r;
        const int tt   = trow & (T_ - 1);
        const int d    = dt * 16 + ql;
        Qh[(size_t)trow * 64 + d] = (_Float16)(accQ[r] * LOG2E);
        {
            const int kt = tt >> 4, qr = tt & 15;
            const int p  = ((d >> 5) << 2) | ((d >> 3) & 3);
            Kf[(((size_t)b * 128 + kt) * 8 + p) * 128 + qr * 8 + (d & 7)]
                = (_Float16)accK[r];
        }
        {
            const int kt5 = tt >> 5, c = tt & 31;
            const int cp  = (c < 16) ? (8 * (c >> 2) + (c & 3))
                                     : (8 * ((c & 15) >> 2) + 4 + (c & 3));
            Vf[(((((size_t)b * 64 + kt5) * 4 + dt) * 16 + ql) * 4 + (cp >> 3)) * 8 + (cp & 7)]
                = (_Float16)accV[r];
        }
    }
}

// One q-tile's 32-key step, fully flattened into named registers.
// qf0/qf1: Q fragment; a0..a3: f32x4 accumulators; mr: running max (base-2);
// ls: per-lane lsum partial. Uses k0lo..k1hi, v0..v3, R0..R3 from scope.
#define PROC(qf0, qf1, a0, a1, a2, a3, mr, ls)                               \
    do {                                                                     \
        f32x4 s0 = {0.f, 0.f, 0.f, 0.f};                                     \
        f32x4 s1 = {0.f, 0.f, 0.f, 0.f};                                     \
        s0 = MFMA16(k0lo, qf0, s0);                                          \
        s0 = MFMA16(k0hi, qf1, s0);                                          \
        s1 = MFMA16(k1lo, qf0, s1);                                          \
        s1 = MFMA16(k1hi, qf1, s1);                                          \
        const float p0 = s0[0], p1 = s0[1], p2 = s0[2], p3 = s0[3];          \
        const float p4 = s1[0], p5 = s1[1], p6 = s1[2], p7 = s1[3];          \
        const float q0_ = fmaxf(fmaxf(p0, p1), p2);                          \
        const float q1_ = fmaxf(fmaxf(p3, p4), p5);                          \
        const float q2_ = fmaxf(fmaxf(p6, p7), q0_);                         \
        const float pm  = fmaxf(q1_, q2_);                                   \
        if (__any(pm - mr > 8.0f)) {                                         \
            float pmw = fmaxf(pm, __shfl_xor(pm, 16));                       \
            pmw = fmaxf(pmw, __shfl_xor(pmw, 32));                           \
            const float mnew = fmaxf(mr, pmw);                               \
            const float fac  = xexp2(mr - mnew);                             \
            mr = mnew;                                                       \
            ls *= fac;                                                       \
            const float f0 = __shfl(fac, R0);                                \
            const float f1 = __shfl(fac, R1);                                \
            const float f2 = __shfl(fac, R2);                                \
            const float f3 = __shfl(fac, R3);                                \
            a0[0] *= f0; a0[1] *= f1; a0[2] *= f2; a0[3] *= f3;              \
            a1[0] *= f0; a1[1] *= f1; a1[2] *= f2; a1[3] *= f3;              \
            a2[0] *= f0; a2[1] *= f1; a2[2] *= f2; a2[3] *= f3;              \
            a3[0] *= f0; a3[1] *= f1; a3[2] *= f2; a3[3] *= f3;              \
        }                                                                    \
        const float e0 = xexp2(p0 - mr), e1 = xexp2(p1 - mr);                \
        const float e2 = xexp2(p2 - mr), e3 = xexp2(p3 - mr);                \
        const float e4 = xexp2(p4 - mr), e5 = xexp2(p5 - mr);                \
        const float e6 = xexp2(p6 - mr), e7 = xexp2(p7 - mr);                \
        ls += ((e0 + e1) + (e2 + e3)) + ((e4 + e5) + (e6 + e7));             \
        half8 pav;                                                           \
        pav[0] = (_Float16)e0; pav[1] = (_Float16)e1;                        \
        pav[2] = (_Float16)e2; pav[3] = (_Float16)e3;                        \
        pav[4] = (_Float16)e4; pav[5] = (_Float16)e5;                        \
        pav[6] = (_Float16)e6; pav[7] = (_Float16)e7;                        \
        a0 = MFMA16(pav, v0, a0);                                            \
        a1 = MFMA16(pav, v1, a1);                                            \
        a2 = MFMA16(pav, v2, a2);                                            \
        a3 = MFMA16(pav, v3, a3);                                            \
    } while (0)

// ---------------------------------------------------------------------------
// Kernel 2: flash attention. Grid = 256 blocks x 8 waves (512 thr).
// Same verified structure as R9 (block = 64 q-rows, wave = 4 q-tiles x one
// 256-key split, cross-lane-free steady state), but ALL per-tile state is
// flattened into named registers and __launch_bounds__(512,1) lifts the
// VGPR cap (occupancy is LDS-bound at 1 block/CU = 2 waves/SIMD anyway) —
// eliminating the scratch spill that R6-R9's 44-VGPR compilations imply.
// ---------------------------------------------------------------------------
__global__ __launch_bounds__(512, 1) void attn_kernel(
    const _Float16* __restrict__ Qh, const _Float16* __restrict__ Kf,
    const _Float16* __restrict__ Vf, const float* __restrict__ F,
    float* __restrict__ out)
{
    __shared__ float Ol[8][64][68];    // 139 KB: [split][row][d]
    __shared__ float Ml[8][64];
    __shared__ float Ll[8][64];

    const int lane = threadIdx.x & 63;
    const int wid  = threadIdx.x >> 6;           // 0..7 = key-split
    const int blk  = blockIdx.x;                 // 0..255
    const int b    = blk & 7;                    // XCD-affine batch
    const int tile = blk >> 3;                   // 0..31
    const int ql = lane & 15;
    const int g  = lane >> 4;

    const _Float16* Qbb = Qh + (size_t)b * T_ * 64;
    const half8* KfB = (const half8*)Kf + (size_t)b * 16384;  // 128 tiles * 128
    const half8* VfB = (const half8*)Vf + (size_t)b * 16384;  // 64 tiles * 256

    // Q fragments, named
    const int qb = (tile << 6);
    const half8* qpA = (const half8*)(Qbb + (qb +      ql) * 64);
    const half8* qpB = (const half8*)(Qbb + (qb + 16 + ql) * 64);
    const half8* qpC = (const half8*)(Qbb + (qb + 32 + ql) * 64);
    const half8* qpD = (const half8*)(Qbb + (qb + 48 + ql) * 64);
    const half8 qA0 = qpA[g], qA1 = qpA[4 + g];
    const half8 qB0 = qpB[g], qB1 = qpB[4 + g];
    const half8 qC0 = qpC[g], qC1 = qpC[4 + g];
    const half8 qD0 = qpD[g], qD1 = qpD[4 + g];

    const f32x4 z4 = {0.f, 0.f, 0.f, 0.f};
    f32x4 aA0 = z4, aA1 = z4, aA2 = z4, aA3 = z4;
    f32x4 aB0 = z4, aB1 = z4, aB2 = z4, aB3 = z4;
    f32x4 aC0 = z4, aC1 = z4, aC2 = z4, aC3 = z4;
    f32x4 aD0 = z4, aD1 = z4, aD2 = z4, aD3 = z4;
    float mA = -1e30f, lsA = 0.f;
    float mB = -1e30f, lsB = 0.f;
    float mC = -1e30f, lsC = 0.f;
    float mD = -1e30f, lsD = 0.f;

    const int R0 = (lane & 48) | (4 * g + 0);
    const int R1 = (lane & 48) | (4 * g + 1);
    const int R2 = (lane & 48) | (4 * g + 2);
    const int R3 = (lane & 48) | (4 * g + 3);

    const int kb0 = wid << 8;                    // 256 keys per split
    const half8* kA = KfB + (size_t)(kb0 >> 4) * 128 + g * 16 + ql;
    const half8* vA = VfB + (size_t)(kb0 >> 5) * 256 + ql * 4 + g;

    for (int it = 0; it < 8; ++it) {
        const half8 k0lo = kA[0];
        const half8 k0hi = kA[64];
        const half8 k1lo = kA[128];
        const half8 k1hi = kA[192];
        const half8 v0 = vA[0];
        const half8 v1 = vA[64];
        const half8 v2 = vA[128];
        const half8 v3 = vA[192];
        kA += 256;
        vA += 256;

        PROC(qA0, qA1, aA0, aA1, aA2, aA3, mA, lsA);
        PROC(qB0, qB1, aB0, aB1, aB2, aB3, mB, lsB);
        PROC(qC0, qC1, aC0, aC1, aC2, aC3, mC, lsC);
        PROC(qD0, qD1, aD0, aD1, aD2, aD3, mD, lsD);
    }

    // ---- reduce per-lane lsum partials across the 4 lane-groups ----
    lsA += __shfl_xor(lsA, 16); lsA += __shfl_xor(lsA, 32);
    lsB += __shfl_xor(lsB, 16); lsB += __shfl_xor(lsB, 32);
    lsC += __shfl_xor(lsC, 16); lsC += __shfl_xor(lsC, 32);
    lsD += __shfl_xor(lsD, 16); lsD += __shfl_xor(lsD, 32);

    // ---- write partials to LDS: rows 0..15=A, 16..31=B, 32..47=C, 48..63=D
#pragma unroll
    for (int r = 0; r < 4; ++r) {
        Ol[wid][     4 * g + r][ 0 + ql] = aA0[r];
        Ol[wid][     4 * g + r][16 + ql] = aA1[r];
        Ol[wid][     4 * g + r][32 + ql] = aA2[r];
        Ol[wid][     4 * g + r][48 + ql] = aA3[r];
        Ol[wid][16 + 4 * g + r][ 0 + ql] = aB0[r];
        Ol[wid][16 + 4 * g + r][16 + ql] = aB1[r];
        Ol[wid][16 + 4 * g + r][32 + ql] = aB2[r];
        Ol[wid][16 + 4 * g + r][48 + ql] = aB3[r];
        Ol[wid][32 + 4 * g + r][ 0 + ql] = aC0[r];
        Ol[wid][32 + 4 * g + r][16 + ql] = aC1[r];
        Ol[wid][32 + 4 * g + r][32 + ql] = aC2[r];
        Ol[wid][32 + 4 * g + r][48 + ql] = aC3[r];
        Ol[wid][48 + 4 * g + r][ 0 + ql] = aD0[r];
        Ol[wid][48 + 4 * g + r][16 + ql] = aD1[r];
        Ol[wid][48 + 4 * g + r][32 + ql] = aD2[r];
        Ol[wid][48 + 4 * g + r][48 + ql] = aD3[r];
    }
    if (g == 0) {
        Ml[wid][     ql] = mA;  Ll[wid][     ql] = lsA;
        Ml[wid][16 + ql] = mB;  Ll[wid][16 + ql] = lsB;
        Ml[wid][32 + ql] = mC;  Ll[wid][32 + ql] = lsC;
        Ml[wid][48 + ql] = mD;  Ll[wid][48 + ql] = lsD;
    }
    __syncthreads();

    // ---- combine 8 key-splits; 512 threads, one (row, 8-col chunk) each ----
    const int tid = threadIdx.x;
    const int qq  = tid >> 3;                    // 0..63 row within block
    const int d0  = (tid & 7) * 8;

    float mm[8], lv[8];
#pragma unroll
    for (int s = 0; s < 8; ++s) {
        mm[s] = Ml[s][qq];
        lv[s] = Ll[s][qq];
    }
    float ms = mm[0];
#pragma unroll
    for (int s = 1; s < 8; ++s) ms = fmaxf(ms, mm[s]);
    float lt = 0.f;
    f32x4 oa = {0.f, 0.f, 0.f, 0.f};
    f32x4 ob2 = {0.f, 0.f, 0.f, 0.f};
#pragma unroll
    for (int s = 0; s < 8; ++s) {
        const float sc = xexp2(mm[s] - ms);
        lt += lv[s] * sc;
        oa  += *(const f32x4*)(&Ol[s][qq][d0])     * sc;
        ob2 += *(const f32x4*)(&Ol[s][qq][d0 + 4]) * sc;
    }
    const float inv = 1.0f / lt;
    const size_t grow = (size_t)b * T_ + (tile << 6) + qq;
    const f32x4 fr0 = *(const f32x4*)(F + grow * 64 + d0);
    const f32x4 fr1 = *(const f32x4*)(F + grow * 64 + d0 + 4);
    *(f32x4*)(out + grow * 64 + d0)     = oa * inv + fr0;
    *(f32x4*)(out + grow * 64 + d0 + 4) = ob2 * inv + fr1;
}

extern "C" void kernel_launch(void* const* d_in, const int* in_sizes, int n_in,
                              void* d_out, int out_size, void* d_ws, size_t ws_size,
                              hipStream_t stream)
{
    const float* F  = (const float*)d_in[0];
    const float* WM = (const float*)d_in[1];
    const float* WN = (const float*)d_in[2];
    const float* WV = (const float*)d_in[3];
    float* out = (float*)d_out;

    const size_t proj_bytes = (size_t)B_ * T_ * 64 * sizeof(_Float16); // 2 MB
    char* ws = (char*)d_ws;
    _Float16* Qh = (_Float16*)(ws);
    _Float16* Kf = (_Float16*)(ws + proj_bytes);
    _Float16* Vf = (_Float16*)(ws + 2 * proj_bytes);
    _Float16* Wp = (_Float16*)(ws + 3 * proj_bytes);  // 3*64*64 f16 = 24 KB

    hipLaunchKernelGGL(prepack_kernel, dim3(48), dim3(256), 0, stream,
                       WM, WN, WV, Wp);
    hipLaunchKernelGGL(proj_kernel, dim3(B_ * T_ / 16), dim3(256), 0, stream,
                       F, Wp, Qh, Kf, Vf);
    hipLaunchKernelGGL(attn_kernel, dim3(B_ * T_ / 64), dim3(512), 0, stream,
                       Qh, Kf, Vf, F, out);
}

// Round 11
// 32.521 us; speedup vs baseline: 1.3477x; 1.0531x over previous
//
#include <hip/hip_runtime.h>
#include <hip/hip_bf16.h>

// Problem constants (fixed by reference): B=8, T=2048, C=64
#define B_ 8
#define T_ 2048
#define LOG2E 1.4426950408889634f

typedef _Float16 half8 __attribute__((ext_vector_type(8)));
typedef _Float16 half4 __attribute__((ext_vector_type(4)));
typedef float f32x4 __attribute__((ext_vector_type(4)));

#define MFMA16(A, Bv, Cv) __builtin_amdgcn_mfma_f32_16x16x32_f16((A), (Bv), (Cv), 0, 0, 0)

__device__ inline float xexp2(float x)
{
    float r;
    asm("v_exp_f32 %0, %1" : "=v"(r) : "v"(x));
    return r;
}

// ---------------------------------------------------------------------------
// Kernel 0: pre-pack weights. W [k][d] fp32 -> Wp [mat][d][k] f16.
// ---------------------------------------------------------------------------
__global__ __launch_bounds__(256) void prepack_kernel(
    const float* __restrict__ WM, const float* __restrict__ WN,
    const float* __restrict__ WV, _Float16* __restrict__ Wp)
{
    const int idx = blockIdx.x * 256 + threadIdx.x;   // [0, 12288)
    const int m = idx >> 12;
    const int r = idx & 4095;
    const int d = r >> 6;
    const int k = r & 63;
    const float* W = (m == 0) ? WM : (m == 1) ? WN : WV;
    Wp[m * 4096 + d * 64 + k] = (_Float16)W[k * 64 + d];
}

// ---------------------------------------------------------------------------
// Kernel 1: MFMA projections -> fragment-major K/V layouts. Store-coalesced:
// Q,K computed with SWAPPED MFMA operands (MFMA16(W-frag, F-frag) puts t on
// lanes, d on regs) so each lane's 4 regs are CONTIGUOUS d -> one half4
// (8B) store each. V computed unswapped (lane=d, regs=key) where the
// sigma-permuted key slots cp = 8g + 4*(rt&1) + r are contiguous -> one
// half4 store. 3 stores/thread total (was 13 scattered 2B stores).
// Layout formulas identical to R9/R10 (consumer side untouched).
// ---------------------------------------------------------------------------
__global__ __launch_bounds__(256) void proj_kernel(
    const float* __restrict__ F, const _Float16* __restrict__ Wp,
    _Float16* __restrict__ Qh, _Float16* __restrict__ Kf,
    _Float16* __restrict__ Vf)
{
    const int lane = threadIdx.x & 63;
    const int dt   = threadIdx.x >> 6;            // 0..3 = d-tile
    const int ql = lane & 15;
    const int g  = lane >> 4;
    const int blk = blockIdx.x;                   // 0..1023
    const int b   = blk & 7;                      // XCD-affine batch
    const int rt  = blk >> 3;                     // 0..127 row-tile in batch
    const int rowbase = b * T_ + rt * 16;

    const float* fr = F + (size_t)(rowbase + ql) * 64;
    const f32x4 v00 = *(const f32x4*)(fr + 8 * g);
    const f32x4 v01 = *(const f32x4*)(fr + 8 * g + 4);
    const f32x4 v10 = *(const f32x4*)(fr + 32 + 8 * g);
    const f32x4 v11 = *(const f32x4*)(fr + 32 + 8 * g + 4);
    half8 af0, af1;
#pragma unroll
    for (int j = 0; j < 4; ++j) {
        af0[j]     = (_Float16)v00[j];
        af0[4 + j] = (_Float16)v01[j];
        af1[j]     = (_Float16)v10[j];
        af1[4 + j] = (_Float16)v11[j];
    }

    const half8* wq = (const half8*)(Wp);
    const half8* wk = (const half8*)(Wp + 4096);
    const half8* wv = (const half8*)(Wp + 8192);

    const int fi = (dt * 16 + ql) * 8;
    f32x4 z = {0.f, 0.f, 0.f, 0.f};
    // Q, K swapped: lane = t (row), regs = d
    f32x4 accQ = MFMA16(wq[fi + g], af0, z);
    accQ = MFMA16(wq[fi + 4 + g], af1, accQ);
    f32x4 accK = MFMA16(wk[fi + g], af0, z);
    accK = MFMA16(wk[fi + 4 + g], af1, accK);
    // V unswapped: lane = d, regs = key
    f32x4 accV = MFMA16(af0, wv[fi + g], z);
    accV = MFMA16(af1, wv[fi + 4 + g], accV);

    // ---- Q store: row rowbase+ql, d = dt*16 + 4g + r (contiguous) ----
    {
        half4 qs;
#pragma unroll
        for (int r = 0; r < 4; ++r) qs[r] = (_Float16)(accQ[r] * LOG2E);
        *(half4*)(Qh + (size_t)(rowbase + ql) * 64 + dt * 16 + 4 * g) = qs;
    }
    // ---- K store: kt = rt, qr = ql, d0 = dt*16+4g (d&7 contiguous) ----
    {
        half4 ks;
#pragma unroll
        for (int r = 0; r < 4; ++r) ks[r] = (_Float16)accK[r];
        const int d0 = dt * 16 + 4 * g;
        const int p  = ((d0 >> 5) << 2) | ((d0 >> 3) & 3);
        *(half4*)(Kf + (((size_t)b * 128 + rt) * 8 + p) * 128 + ql * 8 + (d0 & 7)) = ks;
    }
    // ---- V store: d = dt*16+ql, keys -> cp = 8g + 4*(rt&1) + r (contig) ----
    {
        half4 vs;
#pragma unroll
        for (int r = 0; r < 4; ++r) vs[r] = (_Float16)accV[r];
        const int kt5 = rt >> 1;
        const int cp0 = 8 * g + 4 * (rt & 1);
        *(half4*)(Vf + ((((size_t)b * 64 + kt5) * 4 + dt) * 16 + ql) * 32 + cp0) = vs;
    }
}

// One q-tile's 32-key step (R10-verified, flattened named registers).
#define PROC(qf0, qf1, a0, a1, a2, a3, mr, ls)                               \
    do {                                                                     \
        f32x4 s0 = {0.f, 0.f, 0.f, 0.f};                                     \
        f32x4 s1 = {0.f, 0.f, 0.f, 0.f};                                     \
        s0 = MFMA16(k0lo, qf0, s0);                                          \
        s0 = MFMA16(k0hi, qf1, s0);                                          \
        s1 = MFMA16(k1lo, qf0, s1);                                          \
        s1 = MFMA16(k1hi, qf1, s1);                                          \
        const float p0 = s0[0], p1 = s0[1], p2 = s0[2], p3 = s0[3];          \
        const float p4 = s1[0], p5 = s1[1], p6 = s1[2], p7 = s1[3];          \
        const float q0_ = fmaxf(fmaxf(p0, p1), p2);                          \
        const float q1_ = fmaxf(fmaxf(p3, p4), p5);                          \
        const float q2_ = fmaxf(fmaxf(p6, p7), q0_);                         \
        const float pm  = fmaxf(q1_, q2_);                                   \
        if (__any(pm - mr > 8.0f)) {                                         \
            float pmw = fmaxf(pm, __shfl_xor(pm, 16));                       \
            pmw = fmaxf(pmw, __shfl_xor(pmw, 32));                           \
            const float mnew = fmaxf(mr, pmw);                               \
            const float fac  = xexp2(mr - mnew);                             \
            mr = mnew;                                                       \
            ls *= fac;                                                       \
            const int lg = 4 * ((threadIdx.x & 63) >> 4);                    \
            const int lb = (threadIdx.x & 48);                               \
            const float f0 = __shfl(fac, lb | (lg + 0));                     \
            const float f1 = __shfl(fac, lb | (lg + 1));                     \
            const float f2 = __shfl(fac, lb | (lg + 2));                     \
            const float f3 = __shfl(fac, lb | (lg + 3));                     \
            a0[0] *= f0; a0[1] *= f1; a0[2] *= f2; a0[3] *= f3;              \
            a1[0] *= f0; a1[1] *= f1; a1[2] *= f2; a1[3] *= f3;              \
            a2[0] *= f0; a2[1] *= f1; a2[2] *= f2; a2[3] *= f3;              \
            a3[0] *= f0; a3[1] *= f1; a3[2] *= f2; a3[3] *= f3;              \
        }                                                                    \
        const float e0 = xexp2(p0 - mr), e1 = xexp2(p1 - mr);                \
        const float e2 = xexp2(p2 - mr), e3 = xexp2(p3 - mr);                \
        const float e4 = xexp2(p4 - mr), e5 = xexp2(p5 - mr);                \
        const float e6 = xexp2(p6 - mr), e7 = xexp2(p7 - mr);                \
        ls += ((e0 + e1) + (e2 + e3)) + ((e4 + e5) + (e6 + e7));             \
        half8 pav;                                                           \
        pav[0] = (_Float16)e0; pav[1] = (_Float16)e1;                        \
        pav[2] = (_Float16)e2; pav[3] = (_Float16)e3;                        \
        pav[4] = (_Float16)e4; pav[5] = (_Float16)e5;                        \
        pav[6] = (_Float16)e6; pav[7] = (_Float16)e7;                        \
        a0 = MFMA16(pav, v0, a0);                                            \
        a1 = MFMA16(pav, v1, a1);                                            \
        a2 = MFMA16(pav, v2, a2);                                            \
        a3 = MFMA16(pav, v3, a3);                                            \
    } while (0)

// ---------------------------------------------------------------------------
// Kernel 2: flash attention. Grid = 256 blocks x 8 waves (512 thr).
// Wave = TWO 16-row q-tiles (tp = wid&1) x one 512-key split (ks = wid>>1).
// Live VGPR ~110; __launch_bounds__(512,4) caps at 128 -> with Ol[4][64][68]
// (72 KB) this gives 2 blocks/CU = 4 waves/SIMD (2x R10's TLP) to hide the
// softmax dependency chain. Per-SIMD tile-calls unchanged (64).
// ---------------------------------------------------------------------------
__global__ __launch_bounds__(512, 4) void attn_kernel(
    const _Float16* __restrict__ Qh, const _Float16* __restrict__ Kf,
    const _Float16* __restrict__ Vf, const float* __restrict__ F,
    float* __restrict__ out)
{
    __shared__ float Ol[4][64][68];    // ~69.6 KB: [split][row][d]
    __shared__ float Ml[4][64];
    __shared__ float Ll[4][64];

    const int lane = threadIdx.x & 63;
    const int wid  = threadIdx.x >> 6;           // 0..7
    const int tp   = wid & 1;                    // tile-pair
    const int ks   = wid >> 1;                   // 0..3 key-split
    const int blk  = blockIdx.x;                 // 0..255
    const int b    = blk & 7;                    // XCD-affine batch
    const int tile = blk >> 3;                   // 0..31
    const int ql = lane & 15;
    const int g  = lane >> 4;

    const _Float16* Qbb = Qh + (size_t)b * T_ * 64;
    const half8* KfB = (const half8*)Kf + (size_t)b * 16384;  // 128 tiles * 128
    const half8* VfB = (const half8*)Vf + (size_t)b * 16384;  // 64 tiles * 256

    const int qb = (tile << 6) + tp * 32;
    const half8* qpA = (const half8*)(Qbb + (qb +      ql) * 64);
    const half8* qpB = (const half8*)(Qbb + (qb + 16 + ql) * 64);
    const half8 qA0 = qpA[g], qA1 = qpA[4 + g];
    const half8 qB0 = qpB[g], qB1 = qpB[4 + g];

    const f32x4 z4 = {0.f, 0.f, 0.f, 0.f};
    f32x4 aA0 = z4, aA1 = z4, aA2 = z4, aA3 = z4;
    f32x4 aB0 = z4, aB1 = z4, aB2 = z4, aB3 = z4;
    float mA = -1e30f, lsA = 0.f;
    float mB = -1e30f, lsB = 0.f;

    const int kb0 = ks << 9;                     // 512 keys per split
    const half8* kA = KfB + (size_t)(kb0 >> 4) * 128 + g * 16 + ql;
    const half8* vA = VfB + (size_t)(kb0 >> 5) * 256 + ql * 4 + g;

    for (int it = 0; it < 16; ++it) {
        const half8 k0lo = kA[0];
        const half8 k0hi = kA[64];
        const half8 k1lo = kA[128];
        const half8 k1hi = kA[192];
        const half8 v0 = vA[0];
        const half8 v1 = vA[64];
        const half8 v2 = vA[128];
        const half8 v3 = vA[192];
        kA += 256;
        vA += 256;

        PROC(qA0, qA1, aA0, aA1, aA2, aA3, mA, lsA);
        PROC(qB0, qB1, aB0, aB1, aB2, aB3, mB, lsB);
    }

    // ---- reduce per-lane lsum partials across the 4 lane-groups ----
    lsA += __shfl_xor(lsA, 16); lsA += __shfl_xor(lsA, 32);
    lsB += __shfl_xor(lsB, 16); lsB += __shfl_xor(lsB, 32);

    // ---- write partials to LDS (split ks; rows tp*32 + {A:0..15, B:16..31})
#pragma unroll
    for (int r = 0; r < 4; ++r) {
        Ol[ks][tp * 32 +      4 * g + r][ 0 + ql] = aA0[r];
        Ol[ks][tp * 32 +      4 * g + r][16 + ql] = aA1[r];
        Ol[ks][tp * 32 +      4 * g + r][32 + ql] = aA2[r];
        Ol[ks][tp * 32 +      4 * g + r][48 + ql] = aA3[r];
        Ol[ks][tp * 32 + 16 + 4 * g + r][ 0 + ql] = aB0[r];
        Ol[ks][tp * 32 + 16 + 4 * g + r][16 + ql] = aB1[r];
        Ol[ks][tp * 32 + 16 + 4 * g + r][32 + ql] = aB2[r];
        Ol[ks][tp * 32 + 16 + 4 * g + r][48 + ql] = aB3[r];
    }
    if (g == 0) {
        Ml[ks][tp * 32 +      ql] = mA;  Ll[ks][tp * 32 +      ql] = lsA;
        Ml[ks][tp * 32 + 16 + ql] = mB;  Ll[ks][tp * 32 + 16 + ql] = lsB;
    }
    __syncthreads();

    // ---- combine 4 key-splits; 512 threads, one (row, 8-col chunk) each ----
    const int tid = threadIdx.x;
    const int qq  = tid >> 3;                    // 0..63 row within block
    const int d0  = (tid & 7) * 8;

    float mm[4], lv[4];
#pragma unroll
    for (int s = 0; s < 4; ++s) {
        mm[s] = Ml[s][qq];
        lv[s] = Ll[s][qq];
    }
    const float ms = fmaxf(fmaxf(mm[0], mm[1]), fmaxf(mm[2], mm[3]));
    float lt = 0.f;
    f32x4 oa = {0.f, 0.f, 0.f, 0.f};
    f32x4 ob2 = {0.f, 0.f, 0.f, 0.f};
#pragma unroll
    for (int s = 0; s < 4; ++s) {
        const float sc = xexp2(mm[s] - ms);
        lt += lv[s] * sc;
        oa  += *(const f32x4*)(&Ol[s][qq][d0])     * sc;
        ob2 += *(const f32x4*)(&Ol[s][qq][d0 + 4]) * sc;
    }
    const float inv = 1.0f / lt;
    const size_t grow = (size_t)b * T_ + (tile << 6) + qq;
    const f32x4 fr0 = *(const f32x4*)(F + grow * 64 + d0);
    const f32x4 fr1 = *(const f32x4*)(F + grow * 64 + d0 + 4);
    *(f32x4*)(out + grow * 64 + d0)     = oa * inv + fr0;
    *(f32x4*)(out + grow * 64 + d0 + 4) = ob2 * inv + fr1;
}

extern "C" void kernel_launch(void* const* d_in, const int* in_sizes, int n_in,
                              void* d_out, int out_size, void* d_ws, size_t ws_size,
                              hipStream_t stream)
{
    const float* F  = (const float*)d_in[0];
    const float* WM = (const float*)d_in[1];
    const float* WN = (const float*)d_in[2];
    const float* WV = (const float*)d_in[3];
    float* out = (float*)d_out;

    const size_t proj_bytes = (size_t)B_ * T_ * 64 * sizeof(_Float16); // 2 MB
    char* ws = (char*)d_ws;
    _Float16* Qh = (_Float16*)(ws);
    _Float16* Kf = (_Float16*)(ws + proj_bytes);
    _Float16* Vf = (_Float16*)(ws + 2 * proj_bytes);
    _Float16* Wp = (_Float16*)(ws + 3 * proj_bytes);  // 3*64*64 f16 = 24 KB

    hipLaunchKernelGGL(prepack_kernel, dim3(48), dim3(256), 0, stream,
                       WM, WN, WV, Wp);
    hipLaunchKernelGGL(proj_kernel, dim3(B_ * T_ / 16), dim3(256), 0, stream,
                       F, Wp, Qh, Kf, Vf);
    hipLaunchKernelGGL(attn_kernel, dim3(B_ * T_ / 64), dim3(512), 0, stream,
                       Qh, Kf, Vf, F, out);
}

// Round 12
// 32.216 us; speedup vs baseline: 1.3605x; 1.0095x over previous
//
#include <hip/hip_runtime.h>
#include <hip/hip_bf16.h>

// Problem constants (fixed by reference): B=8, T=2048, C=64
#define B_ 8
#define T_ 2048
#define LOG2E 1.4426950408889634f

typedef _Float16 half8 __attribute__((ext_vector_type(8)));
typedef _Float16 half4 __attribute__((ext_vector_type(4)));
typedef float f32x4 __attribute__((ext_vector_type(4)));

#define MFMA16(A, Bv, Cv) __builtin_amdgcn_mfma_f32_16x16x32_f16((A), (Bv), (Cv), 0, 0, 0)

__device__ inline float xexp2(float x)
{
    float r;
    asm("v_exp_f32 %0, %1" : "=v"(r) : "v"(x));
    return r;
}

// ---------------------------------------------------------------------------
// Kernel 0: pre-pack weights. W [k][d] fp32 -> Wp [mat][d][k] f16.
// ---------------------------------------------------------------------------
__global__ __launch_bounds__(256) void prepack_kernel(
    const float* __restrict__ WM, const float* __restrict__ WN,
    const float* __restrict__ WV, _Float16* __restrict__ Wp)
{
    const int idx = blockIdx.x * 256 + threadIdx.x;   // [0, 12288)
    const int m = idx >> 12;
    const int r = idx & 4095;
    const int d = r >> 6;
    const int k = r & 63;
    const float* W = (m == 0) ? WM : (m == 1) ? WN : WV;
    Wp[m * 4096 + d * 64 + k] = (_Float16)W[k * 64 + d];
}

// ---------------------------------------------------------------------------
// Kernel 1: MFMA projections -> fragment-major K/V layouts (R11-verified).
// ---------------------------------------------------------------------------
__global__ __launch_bounds__(256) void proj_kernel(
    const float* __restrict__ F, const _Float16* __restrict__ Wp,
    _Float16* __restrict__ Qh, _Float16* __restrict__ Kf,
    _Float16* __restrict__ Vf)
{
    const int lane = threadIdx.x & 63;
    const int dt   = threadIdx.x >> 6;            // 0..3 = d-tile
    const int ql = lane & 15;
    const int g  = lane >> 4;
    const int blk = blockIdx.x;                   // 0..1023
    const int b   = blk & 7;                      // XCD-affine batch
    const int rt  = blk >> 3;                     // 0..127 row-tile in batch
    const int rowbase = b * T_ + rt * 16;

    const float* fr = F + (size_t)(rowbase + ql) * 64;
    const f32x4 v00 = *(const f32x4*)(fr + 8 * g);
    const f32x4 v01 = *(const f32x4*)(fr + 8 * g + 4);
    const f32x4 v10 = *(const f32x4*)(fr + 32 + 8 * g);
    const f32x4 v11 = *(const f32x4*)(fr + 32 + 8 * g + 4);
    half8 af0, af1;
#pragma unroll
    for (int j = 0; j < 4; ++j) {
        af0[j]     = (_Float16)v00[j];
        af0[4 + j] = (_Float16)v01[j];
        af1[j]     = (_Float16)v10[j];
        af1[4 + j] = (_Float16)v11[j];
    }

    const half8* wq = (const half8*)(Wp);
    const half8* wk = (const half8*)(Wp + 4096);
    const half8* wv = (const half8*)(Wp + 8192);

    const int fi = (dt * 16 + ql) * 8;
    f32x4 z = {0.f, 0.f, 0.f, 0.f};
    // Q, K swapped: lane = t (row), regs = d
    f32x4 accQ = MFMA16(wq[fi + g], af0, z);
    accQ = MFMA16(wq[fi + 4 + g], af1, accQ);
    f32x4 accK = MFMA16(wk[fi + g], af0, z);
    accK = MFMA16(wk[fi + 4 + g], af1, accK);
    // V unswapped: lane = d, regs = key
    f32x4 accV = MFMA16(af0, wv[fi + g], z);
    accV = MFMA16(af1, wv[fi + 4 + g], accV);

    {
        half4 qs;
#pragma unroll
        for (int r = 0; r < 4; ++r) qs[r] = (_Float16)(accQ[r] * LOG2E);
        *(half4*)(Qh + (size_t)(rowbase + ql) * 64 + dt * 16 + 4 * g) = qs;
    }
    {
        half4 ks;
#pragma unroll
        for (int r = 0; r < 4; ++r) ks[r] = (_Float16)accK[r];
        const int d0 = dt * 16 + 4 * g;
        const int p  = ((d0 >> 5) << 2) | ((d0 >> 3) & 3);
        *(half4*)(Kf + (((size_t)b * 128 + rt) * 8 + p) * 128 + ql * 8 + (d0 & 7)) = ks;
    }
    {
        half4 vs;
#pragma unroll
        for (int r = 0; r < 4; ++r) vs[r] = (_Float16)accV[r];
        const int kt5 = rt >> 1;
        const int cp0 = 8 * g + 4 * (rt & 1);
        *(half4*)(Vf + ((((size_t)b * 64 + kt5) * 4 + dt) * 16 + ql) * 32 + cp0) = vs;
    }
}

// One q-tile's 32-key step (R10/R11-verified, flattened named registers).
#define PROC(qf0, qf1, a0, a1, a2, a3, mr, ls)                               \
    do {                                                                     \
        f32x4 s0 = {0.f, 0.f, 0.f, 0.f};                                     \
        f32x4 s1 = {0.f, 0.f, 0.f, 0.f};                                     \
        s0 = MFMA16(k0lo, qf0, s0);                                          \
        s0 = MFMA16(k0hi, qf1, s0);                                          \
        s1 = MFMA16(k1lo, qf0, s1);                                          \
        s1 = MFMA16(k1hi, qf1, s1);                                          \
        const float p0 = s0[0], p1 = s0[1], p2 = s0[2], p3 = s0[3];          \
        const float p4 = s1[0], p5 = s1[1], p6 = s1[2], p7 = s1[3];          \
        const float q0_ = fmaxf(fmaxf(p0, p1), p2);                          \
        const float q1_ = fmaxf(fmaxf(p3, p4), p5);                          \
        const float q2_ = fmaxf(fmaxf(p6, p7), q0_);                         \
        const float pm  = fmaxf(q1_, q2_);                                   \
        if (__any(pm - mr > 8.0f)) {                                         \
            float pmw = fmaxf(pm, __shfl_xor(pm, 16));                       \
            pmw = fmaxf(pmw, __shfl_xor(pmw, 32));                           \
            const float mnew = fmaxf(mr, pmw);                               \
            const float fac  = xexp2(mr - mnew);                             \
            mr = mnew;                                                       \
            ls *= fac;                                                       \
            const int lg = 4 * ((threadIdx.x & 63) >> 4);                    \
            const int lb = (threadIdx.x & 48);                               \
            const float f0 = __shfl(fac, lb | (lg + 0));                     \
            const float f1 = __shfl(fac, lb | (lg + 1));                     \
            const float f2 = __shfl(fac, lb | (lg + 2));                     \
            const float f3 = __shfl(fac, lb | (lg + 3));                     \
            a0[0] *= f0; a0[1] *= f1; a0[2] *= f2; a0[3] *= f3;              \
            a1[0] *= f0; a1[1] *= f1; a1[2] *= f2; a1[3] *= f3;              \
            a2[0] *= f0; a2[1] *= f1; a2[2] *= f2; a2[3] *= f3;              \
            a3[0] *= f0; a3[1] *= f1; a3[2] *= f2; a3[3] *= f3;              \
        }                                                                    \
        const float e0 = xexp2(p0 - mr), e1 = xexp2(p1 - mr);                \
        const float e2 = xexp2(p2 - mr), e3 = xexp2(p3 - mr);                \
        const float e4 = xexp2(p4 - mr), e5 = xexp2(p5 - mr);                \
        const float e6 = xexp2(p6 - mr), e7 = xexp2(p7 - mr);                \
        ls += ((e0 + e1) + (e2 + e3)) + ((e4 + e5) + (e6 + e7));             \
        half8 pav;                                                           \
        pav[0] = (_Float16)e0; pav[1] = (_Float16)e1;                        \
        pav[2] = (_Float16)e2; pav[3] = (_Float16)e3;                        \
        pav[4] = (_Float16)e4; pav[5] = (_Float16)e5;                        \
        pav[6] = (_Float16)e6; pav[7] = (_Float16)e7;                        \
        a0 = MFMA16(pav, v0, a0);                                            \
        a1 = MFMA16(pav, v1, a1);                                            \
        a2 = MFMA16(pav, v2, a2);                                            \
        a3 = MFMA16(pav, v3, a3);                                            \
    } while (0)

// ---------------------------------------------------------------------------
// Kernel 2: flash attention with REGISTER DOUBLE-BUFFERING (T14/G15).
// Grid = 512 blocks x 4 waves (256 thr) -> 2 blocks/CU = 2 waves/SIMD with
// VGPR cap 256 (launch_bounds(256,2)): ~136 live + 32 prefetch regs, no
// spill. Block = 32 q-rows (2 tiles); wave = one 512-key split (ks = wid).
// Each iteration prefetches the NEXT 8 K/V fragments into named registers
// before PROC, so the ~200-300 cyc L2 latency hides under compute instead
// of stalling every iteration (R10/R11: ~500 stall cyc per PROC).
// ---------------------------------------------------------------------------
__global__ __launch_bounds__(256, 2) void attn_kernel(
    const _Float16* __restrict__ Qh, const _Float16* __restrict__ Kf,
    const _Float16* __restrict__ Vf, const float* __restrict__ F,
    float* __restrict__ out)
{
    __shared__ float Ol[4][32][68];    // ~34.8 KB: [split][row][d]
    __shared__ float Ml[4][32];
    __shared__ float Ll[4][32];

    const int lane = threadIdx.x & 63;
    const int wid  = threadIdx.x >> 6;           // 0..3 = key-split
    const int blk  = blockIdx.x;                 // 0..511
    const int b    = blk & 7;                    // XCD-affine batch
    const int tile = blk >> 3;                   // 0..63 (32-row tiles)
    const int ql = lane & 15;
    const int g  = lane >> 4;

    const _Float16* Qbb = Qh + (size_t)b * T_ * 64;
    const half8* KfB = (const half8*)Kf + (size_t)b * 16384;  // 128 tiles * 128
    const half8* VfB = (const half8*)Vf + (size_t)b * 16384;  // 64 tiles * 256

    const int qb = tile * 32;
    const half8* qpA = (const half8*)(Qbb + (qb +      ql) * 64);
    const half8* qpB = (const half8*)(Qbb + (qb + 16 + ql) * 64);
    const half8 qA0 = qpA[g], qA1 = qpA[4 + g];
    const half8 qB0 = qpB[g], qB1 = qpB[4 + g];

    const f32x4 z4 = {0.f, 0.f, 0.f, 0.f};
    f32x4 aA0 = z4, aA1 = z4, aA2 = z4, aA3 = z4;
    f32x4 aB0 = z4, aB1 = z4, aB2 = z4, aB3 = z4;
    float mA = -1e30f, lsA = 0.f;
    float mB = -1e30f, lsB = 0.f;

    const int kb0 = wid << 9;                    // 512 keys per split
    const half8* kA = KfB + (size_t)(kb0 >> 4) * 128 + g * 16 + ql;
    const half8* vA = VfB + (size_t)(kb0 >> 5) * 256 + ql * 4 + g;

    // ---- prologue: load iteration 0's fragments ----
    half8 k0lo = kA[0];
    half8 k0hi = kA[64];
    half8 k1lo = kA[128];
    half8 k1hi = kA[192];
    half8 v0 = vA[0];
    half8 v1 = vA[64];
    half8 v2 = vA[128];
    half8 v3 = vA[192];

    for (int it = 0; it < 16; ++it) {
        // ---- prefetch next iteration's fragments (in flight during PROC)
        half8 nk0lo, nk0hi, nk1lo, nk1hi, nv0, nv1, nv2, nv3;
        if (it < 15) {
            nk0lo = kA[256];
            nk0hi = kA[256 + 64];
            nk1lo = kA[256 + 128];
            nk1hi = kA[256 + 192];
            nv0 = vA[256];
            nv1 = vA[256 + 64];
            nv2 = vA[256 + 128];
            nv3 = vA[256 + 192];
        }

        PROC(qA0, qA1, aA0, aA1, aA2, aA3, mA, lsA);
        PROC(qB0, qB1, aB0, aB1, aB2, aB3, mB, lsB);

        if (it < 15) {
            k0lo = nk0lo; k0hi = nk0hi; k1lo = nk1lo; k1hi = nk1hi;
            v0 = nv0; v1 = nv1; v2 = nv2; v3 = nv3;
        }
        kA += 256;
        vA += 256;
    }

    // ---- reduce per-lane lsum partials across the 4 lane-groups ----
    lsA += __shfl_xor(lsA, 16); lsA += __shfl_xor(lsA, 32);
    lsB += __shfl_xor(lsB, 16); lsB += __shfl_xor(lsB, 32);

    // ---- write partials to LDS (split wid; rows {A:0..15, B:16..31}) ----
#pragma unroll
    for (int r = 0; r < 4; ++r) {
        Ol[wid][     4 * g + r][ 0 + ql] = aA0[r];
        Ol[wid][     4 * g + r][16 + ql] = aA1[r];
        Ol[wid][     4 * g + r][32 + ql] = aA2[r];
        Ol[wid][     4 * g + r][48 + ql] = aA3[r];
        Ol[wid][16 + 4 * g + r][ 0 + ql] = aB0[r];
        Ol[wid][16 + 4 * g + r][16 + ql] = aB1[r];
        Ol[wid][16 + 4 * g + r][32 + ql] = aB2[r];
        Ol[wid][16 + 4 * g + r][48 + ql] = aB3[r];
    }
    if (g == 0) {
        Ml[wid][     ql] = mA;  Ll[wid][     ql] = lsA;
        Ml[wid][16 + ql] = mB;  Ll[wid][16 + ql] = lsB;
    }
    __syncthreads();

    // ---- combine 4 key-splits; 256 threads, one (row, 8-col chunk) each ----
    const int tid = threadIdx.x;
    const int qq  = tid >> 3;                    // 0..31 row within block
    const int d0  = (tid & 7) * 8;

    float mm[4], lv[4];
#pragma unroll
    for (int s = 0; s < 4; ++s) {
        mm[s] = Ml[s][qq];
        lv[s] = Ll[s][qq];
    }
    const float ms = fmaxf(fmaxf(mm[0], mm[1]), fmaxf(mm[2], mm[3]));
    float lt = 0.f;
    f32x4 oa = {0.f, 0.f, 0.f, 0.f};
    f32x4 ob2 = {0.f, 0.f, 0.f, 0.f};
#pragma unroll
    for (int s = 0; s < 4; ++s) {
        const float sc = xexp2(mm[s] - ms);
        lt += lv[s] * sc;
        oa  += *(const f32x4*)(&Ol[s][qq][d0])     * sc;
        ob2 += *(const f32x4*)(&Ol[s][qq][d0 + 4]) * sc;
    }
    const float inv = 1.0f / lt;
    const size_t grow = (size_t)b * T_ + qb + qq;
    const f32x4 fr0 = *(const f32x4*)(F + grow * 64 + d0);
    const f32x4 fr1 = *(const f32x4*)(F + grow * 64 + d0 + 4);
    *(f32x4*)(out + grow * 64 + d0)     = oa * inv + fr0;
    *(f32x4*)(out + grow * 64 + d0 + 4) = ob2 * inv + fr1;
}

extern "C" void kernel_launch(void* const* d_in, const int* in_sizes, int n_in,
                              void* d_out, int out_size, void* d_ws, size_t ws_size,
                              hipStream_t stream)
{
    const float* F  = (const float*)d_in[0];
    const float* WM = (const float*)d_in[1];
    const float* WN = (const float*)d_in[2];
    const float* WV = (const float*)d_in[3];
    float* out = (float*)d_out;

    const size_t proj_bytes = (size_t)B_ * T_ * 64 * sizeof(_Float16); // 2 MB
    char* ws = (char*)d_ws;
    _Float16* Qh = (_Float16*)(ws);
    _Float16* Kf = (_Float16*)(ws + proj_bytes);
    _Float16* Vf = (_Float16*)(ws + 2 * proj_bytes);
    _Float16* Wp = (_Float16*)(ws + 3 * proj_bytes);  // 3*64*64 f16 = 24 KB

    hipLaunchKernelGGL(prepack_kernel, dim3(48), dim3(256), 0, stream,
                       WM, WN, WV, Wp);
    hipLaunchKernelGGL(proj_kernel, dim3(B_ * T_ / 16), dim3(256), 0, stream,
                       F, Wp, Qh, Kf, Vf);
    hipLaunchKernelGGL(attn_kernel, dim3(B_ * T_ / 32), dim3(256), 0, stream,
                       Qh, Kf, Vf, F, out);
}